// Round 1
// baseline (676.276 us; speedup 1.0000x reference)
//
#include <hip/hip_runtime.h>
#include <hip/hip_bf16.h>
#include <math.h>

// ---------------------------------------------------------------------------
// HeterogeneousSupervisedTopicModel forward: recon_loss, other_loss, kld_theta
// B=512, V=50000, K=50, H=300.  All large contractions in bf16 MFMA
// (16x16x32), everything else fp32.  Tolerance is 2% relative -> bf16 safe.
// ---------------------------------------------------------------------------

#define B_  512
#define V_  50000
#define K_  50
#define H_  300
#define HP  320      // padded H (multiple of 64)
#define KP  64       // padded K
#define NSTEP 1563   // ceil(50000/32); step 1562 is the 16-wide tail

typedef __attribute__((ext_vector_type(8))) short short8;
typedef __attribute__((ext_vector_type(4))) float f32x4;

static __device__ __forceinline__ short bf16s(float f) {
  unsigned int u = __builtin_bit_cast(unsigned int, f);
  u += 0x7fffu + ((u >> 16) & 1u);           // RNE
  return (short)(u >> 16);
}

static __device__ __forceinline__ unsigned int pkbf(float lo, float hi) {
  __hip_bfloat162 t = __float22bfloat162_rn(float2{lo, hi});
  unsigned int u; __builtin_memcpy(&u, &t, 4); return u;
}

// 8 consecutive fp32 (two float4) -> bf16x8 fragment (k ascending)
static __device__ __forceinline__ short8 to_bf8(float4 a, float4 b) {
  unsigned int u[4];
  u[0] = pkbf(a.x, a.y); u[1] = pkbf(a.z, a.w);
  u[2] = pkbf(b.x, b.y); u[3] = pkbf(b.z, b.w);
  short8 r; __builtin_memcpy(&r, u, 16); return r;
}

// ---------------------------------------------------------------------------
// k_pre: build SBt (bf16 [64][V], rows 0..49 = (beta*gamma)^T, row 50 = bow_w)
//        build betab (bf16 [V][64], cols 50..63 zero)
//        accumulate sum|gamma|; block 98 computes sum|base_rates|, sum bow_w^2
// accums layout (floats): [0..511] sumexp  [512..1023] lse
//                         [1024]=kld [1025]=gabs [1026]=brabs [1027]=bw2
// ---------------------------------------------------------------------------
__global__ __launch_bounds__(256) void k_pre(
    const float* __restrict__ beta, const float* __restrict__ gamma,
    const float* __restrict__ br,   const float* __restrict__ bw,
    short* __restrict__ SBt, short* __restrict__ betab,
    float* __restrict__ accums)
{
  __shared__ float rA[4], rB[4];
  const int blk = blockIdx.x;
  const int tid = threadIdx.x;
  if (blk < 98) {
    float gabs = 0.f;
    for (int rep = 0; rep < 2; ++rep) {
      int v = blk * 512 + rep * 256 + tid;
      if (v < V_) {
        const float* brow = beta  + (size_t)v * K_;
        const float* grow = gamma + (size_t)v * K_;
        __attribute__((aligned(16))) short tmp[64];
        #pragma unroll
        for (int k = 0; k < K_; ++k) {
          float b = brow[k], g = grow[k];
          gabs += fabsf(g);
          tmp[k] = bf16s(b);
          SBt[(size_t)k * V_ + v] = bf16s(b * g);
        }
        #pragma unroll
        for (int k = K_; k < 64; ++k) tmp[k] = 0;
        SBt[(size_t)50 * V_ + v] = bf16s(bw[v]);
        short8* dst = (short8*)(betab + (size_t)v * 64);
        #pragma unroll
        for (int q = 0; q < 8; ++q) dst[q] = *(const short8*)&tmp[q * 8];
      }
    }
    float t = gabs;
    #pragma unroll
    for (int off = 1; off < 64; off <<= 1) t += __shfl_xor(t, off, 64);
    if ((tid & 63) == 0) atomicAdd(accums + 1025, t);
  } else {
    float s1 = 0.f, s2 = 0.f;
    for (int i = tid; i < V_; i += 256) {
      s1 += fabsf(br[i]);
      float w = bw[i]; s2 += w * w;
    }
    #pragma unroll
    for (int off = 1; off < 64; off <<= 1) {
      s1 += __shfl_xor(s1, off, 64);
      s2 += __shfl_xor(s2, off, 64);
    }
    int wv = tid >> 6;
    if ((tid & 63) == 0) { rA[wv] = s1; rB[wv] = s2; }
    __syncthreads();
    if (tid == 0) {
      float a = 0.f, b = 0.f;
      for (int w = 0; w < 4; ++w) { a += rA[w]; b += rB[w]; }
      accums[1026] = a; accums[1027] = b;
    }
  }
}

// ---------------------------------------------------------------------------
// k_gemm1: part[s][b][h320] += nb[b][v]*W1[h][v] over slab s.  bf16 MFMA,
// 64x64 per wave (4x4 frags), block = 4 waves stacked in m (256b x 64h).
// grid = 2 * 5 * S1.  Cols >=300 hold garbage (ignored by k_kb1).
// ---------------------------------------------------------------------------
__global__ __launch_bounds__(256, 2) void k_gemm1(
    const float* __restrict__ A, const float* __restrict__ W,
    float* __restrict__ part, int sps)
{
  const int blk = blockIdx.x;
  const int bm = blk & 1;
  const int t2 = blk >> 1;
  const int bn = t2 % 5;
  const int s  = t2 / 5;
  const int lane = threadIdx.x & 63;
  const int wv   = threadIdx.x >> 6;
  const int l15  = lane & 15, quad = lane >> 4;
  const int m0 = bm * 256 + wv * 64;
  const int n0 = bn * 64;
  int st0 = s * sps;
  int st1 = st0 + sps; if (st1 > NSTEP) st1 = NSTEP;

  const float* ap[4]; const float* wp[4];
  #pragma unroll
  for (int i = 0; i < 4; ++i) ap[i] = A + (size_t)(m0 + 16 * i + l15) * V_;
  #pragma unroll
  for (int j = 0; j < 4; ++j) {
    int h = n0 + 16 * j + l15; if (h > 299) h = 299;   // clamp; results discarded
    wp[j] = W + (size_t)h * V_;
  }

  f32x4 acc[4][4];
  #pragma unroll
  for (int i = 0; i < 4; ++i)
    #pragma unroll
    for (int j = 0; j < 4; ++j) acc[i][j] = f32x4{0.f, 0.f, 0.f, 0.f};

  const int stm = (st1 < 1562) ? st1 : 1562;   // full 32-wide steps
  for (int st = st0; st < stm; ++st) {
    const int kk = st * 32 + quad * 8;
    short8 af[4], bfv[4];
    #pragma unroll
    for (int i = 0; i < 4; ++i) {
      const float4* p = (const float4*)(ap[i] + kk);
      af[i] = to_bf8(p[0], p[1]);
    }
    #pragma unroll
    for (int j = 0; j < 4; ++j) {
      const float4* p = (const float4*)(wp[j] + kk);
      bfv[j] = to_bf8(p[0], p[1]);
    }
    #pragma unroll
    for (int i = 0; i < 4; ++i)
      #pragma unroll
      for (int j = 0; j < 4; ++j)
        acc[i][j] = __builtin_amdgcn_mfma_f32_16x16x32_bf16(af[i], bfv[j], acc[i][j], 0, 0, 0);
  }
  if (st0 <= 1562 && st1 == NSTEP) {           // tail step (16 valid k)
    const int kk = 1562 * 32 + quad * 8;
    const short8 z = {0, 0, 0, 0, 0, 0, 0, 0};
    short8 af[4], bfv[4];
    #pragma unroll
    for (int i = 0; i < 4; ++i) {
      if (quad < 2) { const float4* p = (const float4*)(ap[i] + kk); af[i] = to_bf8(p[0], p[1]); }
      else af[i] = z;
    }
    #pragma unroll
    for (int j = 0; j < 4; ++j) {
      if (quad < 2) { const float4* p = (const float4*)(wp[j] + kk); bfv[j] = to_bf8(p[0], p[1]); }
      else bfv[j] = z;
    }
    #pragma unroll
    for (int i = 0; i < 4; ++i)
      #pragma unroll
      for (int j = 0; j < 4; ++j)
        acc[i][j] = __builtin_amdgcn_mfma_f32_16x16x32_bf16(af[i], bfv[j], acc[i][j], 0, 0, 0);
  }
  float* op = part + (size_t)s * (B_ * HP);
  #pragma unroll
  for (int i = 0; i < 4; ++i)
    #pragma unroll
    for (int j = 0; j < 4; ++j)
      #pragma unroll
      for (int r = 0; r < 4; ++r)
        op[(size_t)(m0 + 16 * i + quad * 4 + r) * HP + (n0 + 16 * j + l15)] = acc[i][j][r];
}

// ---------------------------------------------------------------------------
// k_kb1: reduce split-K partials + bias + relu + BN1 -> h1 [512][320]
// ---------------------------------------------------------------------------
__global__ __launch_bounds__(256) void k_kb1(
    const float* __restrict__ part, int S1, const float* __restrict__ b1,
    const float* __restrict__ g, const float* __restrict__ bb,
    const float* __restrict__ m, const float* __restrict__ v,
    float* __restrict__ h1)
{
  const int e = blockIdx.x * 256 + threadIdx.x;   // < 512*320
  float s = 0.f;
  for (int i = 0; i < S1; ++i) s += part[(size_t)i * (B_ * HP) + e];
  const int h = e % HP;
  float y = 0.f;
  if (h < H_) {
    float x = s + b1[h];
    x = fmaxf(x, 0.f);
    y = (x - m[h]) * rsqrtf(v[h] + 1e-5f) * g[h] + bb[h];
  }
  h1[e] = y;
}

// ---------------------------------------------------------------------------
// k_kb2: h2 = BN2(relu(h1 @ W2^T + b2)), one block per row b
// ---------------------------------------------------------------------------
__global__ __launch_bounds__(320) void k_kb2(
    const float* __restrict__ h1, const float* __restrict__ W2,
    const float* __restrict__ b2, const float* __restrict__ g,
    const float* __restrict__ bb, const float* __restrict__ m,
    const float* __restrict__ v, float* __restrict__ h2)
{
  __shared__ __attribute__((aligned(16))) float row[H_];
  const int b = blockIdx.x;
  for (int k = threadIdx.x; k < H_; k += 320) row[k] = h1[(size_t)b * HP + k];
  __syncthreads();
  const int h = threadIdx.x;
  if (h < H_) {
    const float4* wr = (const float4*)(W2 + (size_t)h * H_);
    float acc = 0.f;
    for (int q = 0; q < H_ / 4; ++q) {
      float4 w = wr[q];
      float4 r = *(const float4*)&row[q * 4];
      acc += w.x * r.x + w.y * r.y + w.z * r.z + w.w * r.w;
    }
    float x = acc + b2[h];
    x = fmaxf(x, 0.f);
    h2[(size_t)b * HP + h] = (x - m[h]) * rsqrtf(v[h] + 1e-5f) * g[h] + bb[h];
  }
}

// ---------------------------------------------------------------------------
// k_kb3: mu, logsigma, kld partial, theta (softmax) per row; one wave per b.
// writes thetaf fp32 [512][64] and thetab bf16 [512][64] (cols>=50 zero)
// ---------------------------------------------------------------------------
__global__ __launch_bounds__(64) void k_kb3(
    const float* __restrict__ h2, const float* __restrict__ muW,
    const float* __restrict__ mub, const float* __restrict__ lsW,
    const float* __restrict__ lsb, short* __restrict__ thetab,
    float* __restrict__ thetaf, float* __restrict__ scal)
{
  __shared__ __attribute__((aligned(16))) float row[H_];
  const int b = blockIdx.x;
  const int k = threadIdx.x;
  for (int i = k; i < H_; i += 64) row[i] = h2[(size_t)b * HP + i];
  __syncthreads();
  float mu = 0.f, ls = 0.f;
  if (k < K_) {
    const float4* mr = (const float4*)(muW + (size_t)k * H_);
    const float4* lr = (const float4*)(lsW + (size_t)k * H_);
    for (int q = 0; q < H_ / 4; ++q) {
      float4 r = *(const float4*)&row[q * 4];
      float4 a = mr[q]; float4 c = lr[q];
      mu += a.x * r.x + a.y * r.y + a.z * r.z + a.w * r.w;
      ls += c.x * r.x + c.y * r.y + c.z * r.z + c.w * r.w;
    }
    mu += mub[k]; ls += lsb[k];
  }
  // kld contribution
  float term = (k < K_) ? (1.f + ls - mu * mu - __expf(ls)) : 0.f;
  float ts = term;
  #pragma unroll
  for (int off = 1; off < 64; off <<= 1) ts += __shfl_xor(ts, off, 64);
  if (k == 0) atomicAdd(scal, ts * (-0.5f / (float)B_));
  // softmax over K lanes
  float mv = (k < K_) ? mu : -INFINITY;
  #pragma unroll
  for (int off = 1; off < 64; off <<= 1) mv = fmaxf(mv, __shfl_xor(mv, off, 64));
  float e = (k < K_) ? __expf(mu - mv) : 0.f;
  float se = e;
  #pragma unroll
  for (int off = 1; off < 64; off <<= 1) se += __shfl_xor(se, off, 64);
  float th = e / se;
  float tv = (k < K_) ? th : 0.f;
  thetaf[(size_t)b * KP + k] = tv;
  thetab[(size_t)b * KP + k] = bf16s(tv);
}

// ---------------------------------------------------------------------------
// k_c1: sumexp[b] += sum_v exp(theta[b].beta[v] + br[v]).  One 16x16 MFMA
// tile per wave per v-tile (K padded to 64 => 2 MFMA).
// grid = 8 (b-blocks of 64) * 96 (v-slices); 3125 v-tiles total.
// ---------------------------------------------------------------------------
__global__ __launch_bounds__(256, 2) void k_c1(
    const short* __restrict__ thetab, const short* __restrict__ betab,
    const float* __restrict__ br, float* __restrict__ sumexp)
{
  const int blk = blockIdx.x;
  const int bm = blk & 7, vs = blk >> 3;
  const int lane = threadIdx.x & 63, wv = threadIdx.x >> 6;
  const int l15 = lane & 15, quad = lane >> 4;
  const int b0 = bm * 64 + wv * 16;
  const short8* arow = (const short8*)(thetab + (size_t)(b0 + l15) * KP);
  const short8 a0 = arow[quad], a1 = arow[4 + quad];
  int t0 = vs * 33, t1 = t0 + 33; if (t1 > 3125) t1 = 3125;
  float p0 = 0.f, p1 = 0.f, p2 = 0.f, p3 = 0.f;
  for (int tt = t0; tt < t1; ++tt) {
    const int v0 = tt * 16;
    const short8* brow = (const short8*)(betab + (size_t)(v0 + l15) * KP);
    short8 q0 = brow[quad], q1 = brow[4 + quad];
    f32x4 acc = {0.f, 0.f, 0.f, 0.f};
    acc = __builtin_amdgcn_mfma_f32_16x16x32_bf16(a0, q0, acc, 0, 0, 0);
    acc = __builtin_amdgcn_mfma_f32_16x16x32_bf16(a1, q1, acc, 0, 0, 0);
    const float brv = br[v0 + l15];
    p0 += __expf(acc[0] + brv);
    p1 += __expf(acc[1] + brv);
    p2 += __expf(acc[2] + brv);
    p3 += __expf(acc[3] + brv);
  }
  #pragma unroll
  for (int off = 1; off < 16; off <<= 1) {
    p0 += __shfl_xor(p0, off, 16);
    p1 += __shfl_xor(p1, off, 16);
    p2 += __shfl_xor(p2, off, 16);
    p3 += __shfl_xor(p3, off, 16);
  }
  if (l15 == 0) {
    atomicAdd(&sumexp[b0 + quad * 4 + 0], p0);
    atomicAdd(&sumexp[b0 + quad * 4 + 1], p1);
    atomicAdd(&sumexp[b0 + quad * 4 + 2], p2);
    atomicAdd(&sumexp[b0 + quad * 4 + 3], p3);
  }
}

// ---------------------------------------------------------------------------
// k_hetg: parthet[s][b][n64] = slab partial of nb @ SBt^T (n: 0..49 = het
// components, 50 = bow term).  Block = 4 waves, each wave 64b x its 16 n.
// grid = 8 * 64.
// ---------------------------------------------------------------------------
__global__ __launch_bounds__(256, 2) void k_hetg(
    const float* __restrict__ A, const short* __restrict__ SBt,
    float* __restrict__ part, int sps)
{
  const int blk = blockIdx.x;
  const int bm = blk & 7, s = blk >> 3;
  const int lane = threadIdx.x & 63, wv = threadIdx.x >> 6;
  const int l15 = lane & 15, quad = lane >> 4;
  const int m0 = bm * 64;
  const int n0 = wv * 16;
  int st0 = s * sps;
  int st1 = st0 + sps; if (st1 > NSTEP) st1 = NSTEP;

  const float* ap[4];
  #pragma unroll
  for (int i = 0; i < 4; ++i) ap[i] = A + (size_t)(m0 + 16 * i + l15) * V_;
  const short* sp = SBt + (size_t)(n0 + l15) * V_;

  f32x4 acc[4];
  #pragma unroll
  for (int i = 0; i < 4; ++i) acc[i] = f32x4{0.f, 0.f, 0.f, 0.f};

  const int stm = (st1 < 1562) ? st1 : 1562;
  for (int st = st0; st < stm; ++st) {
    const int kk = st * 32 + quad * 8;
    short8 af[4];
    #pragma unroll
    for (int i = 0; i < 4; ++i) {
      const float4* p = (const float4*)(ap[i] + kk);
      af[i] = to_bf8(p[0], p[1]);
    }
    short8 bf = *(const short8*)(sp + kk);
    #pragma unroll
    for (int i = 0; i < 4; ++i)
      acc[i] = __builtin_amdgcn_mfma_f32_16x16x32_bf16(af[i], bf, acc[i], 0, 0, 0);
  }
  if (st0 <= 1562 && st1 == NSTEP) {
    const int kk = 1562 * 32 + quad * 8;
    const short8 z = {0, 0, 0, 0, 0, 0, 0, 0};
    short8 af[4], bf;
    #pragma unroll
    for (int i = 0; i < 4; ++i) {
      if (quad < 2) { const float4* p = (const float4*)(ap[i] + kk); af[i] = to_bf8(p[0], p[1]); }
      else af[i] = z;
    }
    if (quad < 2) bf = *(const short8*)(sp + kk); else bf = z;
    #pragma unroll
    for (int i = 0; i < 4; ++i)
      acc[i] = __builtin_amdgcn_mfma_f32_16x16x32_bf16(af[i], bf, acc[i], 0, 0, 0);
  }
  float* op = part + (size_t)s * (B_ * KP);
  #pragma unroll
  for (int i = 0; i < 4; ++i)
    #pragma unroll
    for (int r = 0; r < 4; ++r)
      op[(size_t)(m0 + 16 * i + quad * 4 + r) * KP + (n0 + l15)] = acc[i][r];
}

// k_d0: hetmat[b][n] = sum_s parthet[s][b][n]
__global__ __launch_bounds__(256) void k_d0(
    const float* __restrict__ part, float* __restrict__ hetmat)
{
  const int e = blockIdx.x * 256 + threadIdx.x;   // < 512*64
  float s = 0.f;
  for (int i = 0; i < 64; ++i) s += part[(size_t)i * (B_ * KP) + e];
  hetmat[e] = s;
}

// ---------------------------------------------------------------------------
// k_d1: finalize lse, expected_pred, mse, other_loss, kld; zero d_out[0]
// ---------------------------------------------------------------------------
__global__ __launch_bounds__(512) void k_d1(
    float* __restrict__ accums, const float* __restrict__ hetmat,
    const float* __restrict__ thetaf, const float* __restrict__ labels,
    const float* __restrict__ topic_w, const float* __restrict__ topic_b,
    const float* __restrict__ bow_b, float* __restrict__ out)
{
  __shared__ float red[8];
  const int b = threadIdx.x;
  const float lseb = __logf(accums[b]);
  accums[512 + b] = lseb;
  float het = 0.f, tpc = 0.f;
  #pragma unroll
  for (int k = 0; k < K_; ++k) {
    float th = thetaf[(size_t)b * KP + k];
    het += th * hetmat[(size_t)b * KP + k];
    tpc += th * topic_w[k];
  }
  float ep = het + hetmat[(size_t)b * KP + 50] + bow_b[0] + tpc + topic_b[0];
  float d = ep - labels[b];
  float sq = d * d;
  #pragma unroll
  for (int off = 1; off < 64; off <<= 1) sq += __shfl_xor(sq, off, 64);
  if ((b & 63) == 0) red[b >> 6] = sq;
  __syncthreads();
  if (b == 0) {
    float tot = 0.f;
    for (int w = 0; w < 8; ++w) tot += red[w];
    float mse = tot / (float)B_;
    out[1] = 0.0005f * accums[1026] + mse + 5e-6f * accums[1025] + 0.0005f * sqrtf(accums[1027]);
    out[2] = accums[1024];
    out[0] = 0.f;   // c2 accumulates recon here
  }
}

// ---------------------------------------------------------------------------
// k_c2: recon accumulation: sum_v log(exp(logit - lse) + 1e-6) * bows
// ---------------------------------------------------------------------------
__global__ __launch_bounds__(256, 2) void k_c2(
    const short* __restrict__ thetab, const short* __restrict__ betab,
    const float* __restrict__ br, const float* __restrict__ lse,
    const float* __restrict__ bows, float* __restrict__ out)
{
  const int blk = blockIdx.x;
  const int bm = blk & 7, vs = blk >> 3;
  const int lane = threadIdx.x & 63, wv = threadIdx.x >> 6;
  const int l15 = lane & 15, quad = lane >> 4;
  const int b0 = bm * 64 + wv * 16;
  const short8* arow = (const short8*)(thetab + (size_t)(b0 + l15) * KP);
  const short8 a0 = arow[quad], a1 = arow[4 + quad];
  float lse4[4]; const float* bro[4];
  #pragma unroll
  for (int r = 0; r < 4; ++r) {
    lse4[r] = lse[b0 + quad * 4 + r];
    bro[r] = bows + (size_t)(b0 + quad * 4 + r) * V_;
  }
  int t0 = vs * 33, t1 = t0 + 33; if (t1 > 3125) t1 = 3125;
  float p = 0.f;
  for (int tt = t0; tt < t1; ++tt) {
    const int v0 = tt * 16;
    const int v = v0 + l15;
    const short8* brow = (const short8*)(betab + (size_t)v * KP);
    short8 q0 = brow[quad], q1 = brow[4 + quad];
    f32x4 acc = {0.f, 0.f, 0.f, 0.f};
    acc = __builtin_amdgcn_mfma_f32_16x16x32_bf16(a0, q0, acc, 0, 0, 0);
    acc = __builtin_amdgcn_mfma_f32_16x16x32_bf16(a1, q1, acc, 0, 0, 0);
    const float brv = br[v];
    #pragma unroll
    for (int r = 0; r < 4; ++r) {
      float l = acc[r] + brv - lse4[r];
      float pr = __logf(__expf(l) + 1e-6f);
      p += pr * bro[r][v];
    }
  }
  #pragma unroll
  for (int off = 1; off < 64; off <<= 1) p += __shfl_xor(p, off, 64);
  if (lane == 0) atomicAdd(out, -p * (1.0f / (float)B_));
}

// ---------------------------------------------------------------------------
extern "C" void kernel_launch(void* const* d_in, const int* in_sizes, int n_in,
                              void* d_out, int out_size, void* d_ws, size_t ws_size,
                              hipStream_t stream)
{
  const float* bows    = (const float*)d_in[0];
  const float* nb      = (const float*)d_in[1];
  const float* labels  = (const float*)d_in[2];
  const float* W1      = (const float*)d_in[3];
  const float* b1      = (const float*)d_in[4];
  const float* W2      = (const float*)d_in[5];
  const float* b2      = (const float*)d_in[6];
  const float* bn1_g   = (const float*)d_in[7];
  const float* bn1_b   = (const float*)d_in[8];
  const float* bn1_m   = (const float*)d_in[9];
  const float* bn1_v   = (const float*)d_in[10];
  const float* bn2_g   = (const float*)d_in[11];
  const float* bn2_b   = (const float*)d_in[12];
  const float* bn2_m   = (const float*)d_in[13];
  const float* bn2_v   = (const float*)d_in[14];
  const float* muW     = (const float*)d_in[15];
  const float* mub     = (const float*)d_in[16];
  const float* lsW     = (const float*)d_in[17];
  const float* lsb     = (const float*)d_in[18];
  const float* beta    = (const float*)d_in[19];
  const float* gamma   = (const float*)d_in[20];
  const float* brates  = (const float*)d_in[21];
  const float* bow_w   = (const float*)d_in[22];
  const float* bow_b   = (const float*)d_in[23];
  const float* topic_w = (const float*)d_in[24];
  const float* topic_b = (const float*)d_in[25];
  float* out = (float*)d_out;

  char* ws = (char*)d_ws;
  size_t off = 0;
  auto take = [&](size_t bytes) { void* p = ws + off; off = (off + bytes + 255) & ~(size_t)255; return p; };

  float* parthet = (float*)take((size_t)64 * B_ * KP * 4);   // 8 MB
  float* h1      = (float*)take((size_t)B_ * HP * 4);
  float* h2      = (float*)take((size_t)B_ * HP * 4);
  short* thetab  = (short*)take((size_t)B_ * KP * 2);
  float* thetaf  = (float*)take((size_t)B_ * KP * 4);
  short* SBt     = (short*)take((size_t)64 * V_ * 2);        // 6.4 MB
  short* betab   = (short*)take((size_t)V_ * 64 * 2);        // 6.4 MB
  float* hetmat  = (float*)take((size_t)B_ * KP * 4);
  float* accums  = (float*)take(4352);
  float* part1   = (float*)(ws + off);
  size_t remain = (ws_size > off) ? (ws_size - off) : 0;
  int S1 = (int)(remain / ((size_t)B_ * HP * 4));
  if (S1 > 48) S1 = 48;
  if (S1 < 1)  S1 = 1;
  const int sps1 = (NSTEP + S1 - 1) / S1;
  const int spsh = (NSTEP + 63) / 64;

  hipMemsetAsync(accums, 0, 4352, stream);
  k_pre  <<<99, 256, 0, stream>>>(beta, gamma, brates, bow_w, SBt, betab, accums);
  k_gemm1<<<10 * S1, 256, 0, stream>>>(nb, W1, part1, sps1);
  k_kb1  <<<(B_ * HP) / 256, 256, 0, stream>>>(part1, S1, b1, bn1_g, bn1_b, bn1_m, bn1_v, h1);
  k_kb2  <<<B_, 320, 0, stream>>>(h1, W2, b2, bn2_g, bn2_b, bn2_m, bn2_v, h2);
  k_kb3  <<<B_, 64, 0, stream>>>(h2, muW, mub, lsW, lsb, thetab, thetaf, accums + 1024);
  k_c1   <<<8 * 96, 256, 0, stream>>>(thetab, betab, brates, accums);
  k_hetg <<<8 * 64, 256, 0, stream>>>(nb, SBt, parthet, spsh);
  k_d0   <<<(B_ * KP) / 256, 256, 0, stream>>>(parthet, hetmat);
  k_d1   <<<1, 512, 0, stream>>>(accums, hetmat, thetaf, labels, topic_w, topic_b, bow_b, out);
  k_c2   <<<8 * 96, 256, 0, stream>>>(thetab, betab, brates, accums + 512, bows, out);
}

// Round 2
// 653.892 us; speedup vs baseline: 1.0342x; 1.0342x over previous
//
#include <hip/hip_runtime.h>
#include <hip/hip_bf16.h>
#include <math.h>

// ---------------------------------------------------------------------------
// HeterogeneousSupervisedTopicModel fwd: recon_loss, other_loss, kld_theta
// B=512, V=50000, K=50, H=300.  Round 2: fused big-GEMM (encoder L1 + het +
// bow terms) with register-level software pipelining; prep pass builds a
// bf16 Wcat [384][50016] so the GEMM inner loop is load->mfma only on the
// B side and load->cvt->mfma on the A side.
// ---------------------------------------------------------------------------

#define B_  512
#define V_  50000
#define VP  50016    // K padded to multiple of 32 (zero-filled in Wcat)
#define K_  50
#define H_  300
#define HP  320
#define KP  64
#define NW  384      // Wcat rows: 0..299 W1, 320..369 beta*gamma, 370 bow_w
#define NSTEP 1563   // VP/32

typedef __attribute__((ext_vector_type(8))) short short8;
typedef __attribute__((ext_vector_type(4))) float f32x4;

static __device__ __forceinline__ short bf16s(float f) {
  unsigned int u = __builtin_bit_cast(unsigned int, f);
  u += 0x7fffu + ((u >> 16) & 1u);
  return (short)(u >> 16);
}

static __device__ __forceinline__ unsigned int pkbf(float lo, float hi) {
  __hip_bfloat162 t = __float22bfloat162_rn(float2{lo, hi});
  unsigned int u; __builtin_memcpy(&u, &t, 4); return u;
}

static __device__ __forceinline__ short8 to_bf8(float4 a, float4 b) {
  unsigned int u[4];
  u[0] = pkbf(a.x, a.y); u[1] = pkbf(a.z, a.w);
  u[2] = pkbf(b.x, b.y); u[3] = pkbf(b.z, b.w);
  short8 r; __builtin_memcpy(&r, u, 16); return r;
}

// ---------------------------------------------------------------------------
// k_cvtW: Wcat rows 0..299 = bf16(W1), cols >= 50000 zero.  Fully coalesced.
// ---------------------------------------------------------------------------
__global__ __launch_bounds__(256) void k_cvtW(
    const float* __restrict__ W1, short* __restrict__ Wcat)
{
  const int idx = blockIdx.x * 256 + threadIdx.x;     // < 300*6252
  if (idx >= 300 * (VP / 8)) return;
  const int r = idx / (VP / 8);
  const int c = (idx - r * (VP / 8)) * 8;
  short8 out;
  if (c + 8 <= V_) {
    const float4* p = (const float4*)(W1 + (size_t)r * V_ + c);
    out = to_bf8(p[0], p[1]);
  } else {
    out = short8{0, 0, 0, 0, 0, 0, 0, 0};             // pure pad (V_%8==0)
  }
  *(short8*)(Wcat + (size_t)r * VP + c) = out;
}

// ---------------------------------------------------------------------------
// k_sb: per 64-v tile, LDS-transpose beta/gamma, write
//   Wcat rows 300..383: 300..319 zero, 320..369 bf16(beta*gamma)^T,
//                       370 bf16(bow_w), 371..383 zero (cols>=50000 zero)
//   betab [V][64] bf16(beta), cols 50..63 zero
//   accumulate sum|gamma| -> accums[1025]
// block 782 (last) computes sum|base_rates| -> [1026], sum bow_w^2 -> [1027]
// ---------------------------------------------------------------------------
__global__ __launch_bounds__(256) void k_sb(
    const float* __restrict__ beta, const float* __restrict__ gamma,
    const float* __restrict__ br,   const float* __restrict__ bw,
    short* __restrict__ Wcat, short* __restrict__ betab,
    float* __restrict__ accums)
{
  __shared__ float bt[64 * 51];
  __shared__ float gt[64 * 51];
  __shared__ float red[4], red2[4];
  const int tid = threadIdx.x;
  const int blk = blockIdx.x;
  if (blk == 782) {
    float s1 = 0.f, s2 = 0.f;
    for (int i = tid; i < V_; i += 256) {
      s1 += fabsf(br[i]);
      float w = bw[i]; s2 += w * w;
    }
    #pragma unroll
    for (int off = 1; off < 64; off <<= 1) {
      s1 += __shfl_xor(s1, off, 64);
      s2 += __shfl_xor(s2, off, 64);
    }
    if ((tid & 63) == 0) { red[tid >> 6] = s1; red2[tid >> 6] = s2; }
    __syncthreads();
    if (tid == 0) {
      float a = 0.f, b = 0.f;
      for (int w = 0; w < 4; ++w) { a += red[w]; b += red2[w]; }
      accums[1026] = a; accums[1027] = b;
    }
    return;
  }
  const int v0 = blk * 64;
  const int nvalid = (V_ - v0 < 64) ? (V_ - v0) : 64;          // loadable v
  const int nwrite = (VP - v0 < 64) ? (VP - v0) : 64;          // writable cols
  const int total = nvalid * 50;
  float gabs = 0.f;
  for (int f = tid; f < total; f += 256) {
    int j = f / 50, k = f - j * 50;
    bt[j * 51 + k] = beta[(size_t)v0 * 50 + f];
    float g = gamma[(size_t)v0 * 50 + f];
    gt[j * 51 + k] = g;
    gabs += fabsf(g);
  }
  // reduce gabs
  #pragma unroll
  for (int off = 1; off < 64; off <<= 1) gabs += __shfl_xor(gabs, off, 64);
  if ((tid & 63) == 0) atomicAdd(accums + 1025, gabs);
  __syncthreads();

  const int j = tid & 63;
  const int q = tid >> 6;
  // Wcat rows 300..383
  #pragma unroll
  for (int p = 0; p < 21; ++p) {
    const int kk = p * 4 + q;          // 0..83
    if (j < nwrite) {
      short val = 0;
      if (j < nvalid) {
        if (kk >= 20 && kk < 70) {
          int k2 = kk - 20;
          val = bf16s(bt[j * 51 + k2] * gt[j * 51 + k2]);
        } else if (kk == 70) {
          val = bf16s(bw[v0 + j]);
        }
      }
      Wcat[(size_t)(300 + kk) * VP + v0 + j] = val;
    }
  }
  // betab rows v0+j (only valid v)
  if (j < nvalid) {
    __attribute__((aligned(16))) short tmp[16];
    #pragma unroll
    for (int t = 0; t < 16; ++t) {
      int k = q * 16 + t;
      tmp[t] = (k < K_) ? bf16s(bt[j * 51 + k]) : (short)0;
    }
    short8* dst = (short8*)(betab + (size_t)(v0 + j) * 64 + q * 16);
    dst[0] = *(const short8*)&tmp[0];
    dst[1] = *(const short8*)&tmp[8];
  }
}

// ---------------------------------------------------------------------------
// k_bg: part[s][512][384] = slab-partial of nb(fp32) @ Wcat^T(bf16).
// Block = 4 waves (2m x 2n), block tile 128x128, wave tile 64x64.
// Register double-buffer: load step t+1 while MFMA'ing step t.
// grid = 12 * S.
// ---------------------------------------------------------------------------
__global__ __launch_bounds__(256, 2) void k_bg(
    const float* __restrict__ A, const short* __restrict__ Wcat,
    float* __restrict__ part, int sps)
{
  const int t = blockIdx.x;
  const int s = t / 12;
  const int r = t % 12;
  const int bmi = r & 3, bni = r >> 2;
  const int lane = threadIdx.x & 63, wv = threadIdx.x >> 6;
  const int l15 = lane & 15, quad = lane >> 4;
  const int m0 = bmi * 128 + (wv & 1) * 64;
  const int n0 = bni * 128 + (wv >> 1) * 64;
  int st0 = s * sps;
  int st1 = st0 + sps; if (st1 > NSTEP) st1 = NSTEP;

  const float* ap[4]; const short* bp[4];
  #pragma unroll
  for (int i = 0; i < 4; ++i) ap[i] = A + (size_t)(m0 + 16 * i + l15) * V_;
  #pragma unroll
  for (int jj = 0; jj < 4; ++jj) bp[jj] = Wcat + (size_t)(n0 + 16 * jj + l15) * VP;

  f32x4 acc[4][4];
  #pragma unroll
  for (int i = 0; i < 4; ++i)
    #pragma unroll
    for (int jj = 0; jj < 4; ++jj) acc[i][jj] = f32x4{0.f, 0.f, 0.f, 0.f};

  float4 A0[4][2], A1[4][2];
  short8 B0[4], B1[4];

  auto ld = [&](int st, float4 (&Ar)[4][2], short8 (&Br)[4]) {
    const int kk = st * 32 + quad * 8;
    if (st != 1562) {
      #pragma unroll
      for (int i = 0; i < 4; ++i) {
        const float4* p = (const float4*)(ap[i] + kk);
        Ar[i][0] = p[0]; Ar[i][1] = p[1];
      }
    } else {                                   // tail: k>=50000 invalid for A
      const float4 z{0.f, 0.f, 0.f, 0.f};
      #pragma unroll
      for (int i = 0; i < 4; ++i) {
        if (quad < 2) {
          const float4* p = (const float4*)(ap[i] + kk);
          Ar[i][0] = p[0]; Ar[i][1] = p[1];
        } else { Ar[i][0] = z; Ar[i][1] = z; }
      }
    }
    #pragma unroll
    for (int jj = 0; jj < 4; ++jj) Br[jj] = *(const short8*)(bp[jj] + kk);
  };
  auto comp = [&](float4 (&Ar)[4][2], short8 (&Br)[4]) {
    short8 af[4];
    #pragma unroll
    for (int i = 0; i < 4; ++i) af[i] = to_bf8(Ar[i][0], Ar[i][1]);
    #pragma unroll
    for (int i = 0; i < 4; ++i)
      #pragma unroll
      for (int jj = 0; jj < 4; ++jj)
        acc[i][jj] = __builtin_amdgcn_mfma_f32_16x16x32_bf16(af[i], Br[jj], acc[i][jj], 0, 0, 0);
  };

  if (st0 < st1) {
    ld(st0, A0, B0);
    int st = st0;
    for (; st + 2 <= st1; st += 2) {
      ld(st + 1, A1, B1);
      comp(A0, B0);
      if (st + 2 < st1) ld(st + 2, A0, B0);
      comp(A1, B1);
    }
    if (st < st1) comp(A0, B0);
  }
  float* op = part + (size_t)s * (B_ * NW);
  #pragma unroll
  for (int i = 0; i < 4; ++i)
    #pragma unroll
    for (int jj = 0; jj < 4; ++jj)
      #pragma unroll
      for (int rr = 0; rr < 4; ++rr)
        op[(size_t)(m0 + 16 * i + quad * 4 + rr) * NW + (n0 + 16 * jj + l15)] = acc[i][jj][rr];
}

// ---------------------------------------------------------------------------
// k_red: sum S slabs; n<300 -> bias/relu/BN1 -> h1;  320<=n<=370 -> hetmat
// ---------------------------------------------------------------------------
__global__ __launch_bounds__(256) void k_red(
    const float* __restrict__ part, int S, const float* __restrict__ b1,
    const float* __restrict__ g, const float* __restrict__ bb,
    const float* __restrict__ m, const float* __restrict__ v,
    float* __restrict__ h1, float* __restrict__ hetmat)
{
  const int e = blockIdx.x * 256 + threadIdx.x;   // < 512*384
  float s = 0.f;
  for (int i = 0; i < S; ++i) s += part[(size_t)i * (B_ * NW) + e];
  const int n = e % NW, b = e / NW;
  if (n < H_) {
    float x = s + b1[n];
    x = fmaxf(x, 0.f);
    h1[(size_t)b * HP + n] = (x - m[n]) * rsqrtf(v[n] + 1e-5f) * g[n] + bb[n];
  } else if (n >= 320 && n <= 370) {
    hetmat[(size_t)b * KP + (n - 320)] = s;
  }
}

// ---------------------------------------------------------------------------
// k_kb2: h2 = BN2(relu(h1 @ W2^T + b2)), one block per row b
// ---------------------------------------------------------------------------
__global__ __launch_bounds__(320) void k_kb2(
    const float* __restrict__ h1, const float* __restrict__ W2,
    const float* __restrict__ b2, const float* __restrict__ g,
    const float* __restrict__ bb, const float* __restrict__ m,
    const float* __restrict__ v, float* __restrict__ h2)
{
  __shared__ __attribute__((aligned(16))) float row[H_];
  const int b = blockIdx.x;
  for (int k = threadIdx.x; k < H_; k += 320) row[k] = h1[(size_t)b * HP + k];
  __syncthreads();
  const int h = threadIdx.x;
  if (h < H_) {
    const float4* wr = (const float4*)(W2 + (size_t)h * H_);
    float acc = 0.f;
    for (int q = 0; q < H_ / 4; ++q) {
      float4 w = wr[q];
      float4 rr = *(const float4*)&row[q * 4];
      acc += w.x * rr.x + w.y * rr.y + w.z * rr.z + w.w * rr.w;
    }
    float x = acc + b2[h];
    x = fmaxf(x, 0.f);
    h2[(size_t)b * HP + h] = (x - m[h]) * rsqrtf(v[h] + 1e-5f) * g[h] + bb[h];
  }
}

// ---------------------------------------------------------------------------
// k_kb3: mu, logsigma, kld partial, theta softmax; one wave per b
// ---------------------------------------------------------------------------
__global__ __launch_bounds__(64) void k_kb3(
    const float* __restrict__ h2, const float* __restrict__ muW,
    const float* __restrict__ mub, const float* __restrict__ lsW,
    const float* __restrict__ lsb, short* __restrict__ thetab,
    float* __restrict__ thetaf, float* __restrict__ scal)
{
  __shared__ __attribute__((aligned(16))) float row[H_];
  const int b = blockIdx.x;
  const int k = threadIdx.x;
  for (int i = k; i < H_; i += 64) row[i] = h2[(size_t)b * HP + i];
  __syncthreads();
  float mu = 0.f, ls = 0.f;
  if (k < K_) {
    const float4* mr = (const float4*)(muW + (size_t)k * H_);
    const float4* lr = (const float4*)(lsW + (size_t)k * H_);
    for (int q = 0; q < H_ / 4; ++q) {
      float4 rr = *(const float4*)&row[q * 4];
      float4 a = mr[q]; float4 c = lr[q];
      mu += a.x * rr.x + a.y * rr.y + a.z * rr.z + a.w * rr.w;
      ls += c.x * rr.x + c.y * rr.y + c.z * rr.z + c.w * rr.w;
    }
    mu += mub[k]; ls += lsb[k];
  }
  float term = (k < K_) ? (1.f + ls - mu * mu - __expf(ls)) : 0.f;
  float ts = term;
  #pragma unroll
  for (int off = 1; off < 64; off <<= 1) ts += __shfl_xor(ts, off, 64);
  if (k == 0) atomicAdd(scal, ts * (-0.5f / (float)B_));
  float mv = (k < K_) ? mu : -INFINITY;
  #pragma unroll
  for (int off = 1; off < 64; off <<= 1) mv = fmaxf(mv, __shfl_xor(mv, off, 64));
  float e = (k < K_) ? __expf(mu - mv) : 0.f;
  float se = e;
  #pragma unroll
  for (int off = 1; off < 64; off <<= 1) se += __shfl_xor(se, off, 64);
  float th = e / se;
  float tv = (k < K_) ? th : 0.f;
  thetaf[(size_t)b * KP + k] = tv;
  thetab[(size_t)b * KP + k] = bf16s(tv);
}

// ---------------------------------------------------------------------------
// k_c1: sumexp[b] += sum_v exp(theta[b].beta[v] + br[v]); 2-tile unroll
// ---------------------------------------------------------------------------
__global__ __launch_bounds__(256, 2) void k_c1(
    const short* __restrict__ thetab, const short* __restrict__ betab,
    const float* __restrict__ br, float* __restrict__ sumexp)
{
  const int blk = blockIdx.x;
  const int bm = blk & 7, vs = blk >> 3;
  const int lane = threadIdx.x & 63, wv = threadIdx.x >> 6;
  const int l15 = lane & 15, quad = lane >> 4;
  const int b0 = bm * 64 + wv * 16;
  const short8* arow = (const short8*)(thetab + (size_t)(b0 + l15) * KP);
  const short8 a0 = arow[quad], a1 = arow[4 + quad];
  int t0 = vs * 33, t1 = t0 + 33; if (t1 > 3125) t1 = 3125;
  float p0 = 0.f, p1 = 0.f, p2 = 0.f, p3 = 0.f;
  auto body = [&](int tt) {
    const int v0 = tt * 16;
    const short8* brow = (const short8*)(betab + (size_t)(v0 + l15) * KP);
    short8 q0 = brow[quad], q1 = brow[4 + quad];
    f32x4 acc = {0.f, 0.f, 0.f, 0.f};
    acc = __builtin_amdgcn_mfma_f32_16x16x32_bf16(a0, q0, acc, 0, 0, 0);
    acc = __builtin_amdgcn_mfma_f32_16x16x32_bf16(a1, q1, acc, 0, 0, 0);
    const float brv = br[v0 + l15];
    p0 += __expf(acc[0] + brv);
    p1 += __expf(acc[1] + brv);
    p2 += __expf(acc[2] + brv);
    p3 += __expf(acc[3] + brv);
  };
  int tt = t0;
  for (; tt + 2 <= t1; tt += 2) { body(tt); body(tt + 1); }
  if (tt < t1) body(tt);
  #pragma unroll
  for (int off = 1; off < 16; off <<= 1) {
    p0 += __shfl_xor(p0, off, 16);
    p1 += __shfl_xor(p1, off, 16);
    p2 += __shfl_xor(p2, off, 16);
    p3 += __shfl_xor(p3, off, 16);
  }
  if (l15 == 0) {
    atomicAdd(&sumexp[b0 + quad * 4 + 0], p0);
    atomicAdd(&sumexp[b0 + quad * 4 + 1], p1);
    atomicAdd(&sumexp[b0 + quad * 4 + 2], p2);
    atomicAdd(&sumexp[b0 + quad * 4 + 3], p3);
  }
}

// ---------------------------------------------------------------------------
// k_d1: finalize lse, expected_pred, mse, other_loss, kld; zero out[0]
// ---------------------------------------------------------------------------
__global__ __launch_bounds__(512) void k_d1(
    float* __restrict__ accums, const float* __restrict__ hetmat,
    const float* __restrict__ thetaf, const float* __restrict__ labels,
    const float* __restrict__ topic_w, const float* __restrict__ topic_b,
    const float* __restrict__ bow_b, float* __restrict__ out)
{
  __shared__ float red[8];
  const int b = threadIdx.x;
  const float lseb = __logf(accums[b]);
  accums[512 + b] = lseb;
  float het = 0.f, tpc = 0.f;
  #pragma unroll
  for (int k = 0; k < K_; ++k) {
    float th = thetaf[(size_t)b * KP + k];
    het += th * hetmat[(size_t)b * KP + k];
    tpc += th * topic_w[k];
  }
  float ep = het + hetmat[(size_t)b * KP + 50] + bow_b[0] + tpc + topic_b[0];
  float d = ep - labels[b];
  float sq = d * d;
  #pragma unroll
  for (int off = 1; off < 64; off <<= 1) sq += __shfl_xor(sq, off, 64);
  if ((b & 63) == 0) red[b >> 6] = sq;
  __syncthreads();
  if (b == 0) {
    float tot = 0.f;
    for (int w = 0; w < 8; ++w) tot += red[w];
    float mse = tot / (float)B_;
    out[1] = 0.0005f * accums[1026] + mse + 5e-6f * accums[1025] + 0.0005f * sqrtf(accums[1027]);
    out[2] = accums[1024];
    out[0] = 0.f;
  }
}

// ---------------------------------------------------------------------------
// k_c2: recon accumulation: -mean_b sum_v log(exp(logit-lse)+1e-6)*bows
// ---------------------------------------------------------------------------
__global__ __launch_bounds__(256, 2) void k_c2(
    const short* __restrict__ thetab, const short* __restrict__ betab,
    const float* __restrict__ br, const float* __restrict__ lse,
    const float* __restrict__ bows, float* __restrict__ out)
{
  const int blk = blockIdx.x;
  const int bm = blk & 7, vs = blk >> 3;
  const int lane = threadIdx.x & 63, wv = threadIdx.x >> 6;
  const int l15 = lane & 15, quad = lane >> 4;
  const int b0 = bm * 64 + wv * 16;
  const short8* arow = (const short8*)(thetab + (size_t)(b0 + l15) * KP);
  const short8 a0 = arow[quad], a1 = arow[4 + quad];
  float lse4[4]; const float* bro[4];
  #pragma unroll
  for (int rr = 0; rr < 4; ++rr) {
    lse4[rr] = lse[b0 + quad * 4 + rr];
    bro[rr] = bows + (size_t)(b0 + quad * 4 + rr) * V_;
  }
  int t0 = vs * 33, t1 = t0 + 33; if (t1 > 3125) t1 = 3125;
  float p = 0.f;
  auto body = [&](int tt) {
    const int v0 = tt * 16;
    const int v = v0 + l15;
    const short8* brow = (const short8*)(betab + (size_t)v * KP);
    short8 q0 = brow[quad], q1 = brow[4 + quad];
    f32x4 acc = {0.f, 0.f, 0.f, 0.f};
    acc = __builtin_amdgcn_mfma_f32_16x16x32_bf16(a0, q0, acc, 0, 0, 0);
    acc = __builtin_amdgcn_mfma_f32_16x16x32_bf16(a1, q1, acc, 0, 0, 0);
    const float brv = br[v];
    #pragma unroll
    for (int rr = 0; rr < 4; ++rr) {
      float l = acc[rr] + brv - lse4[rr];
      float pr = __logf(__expf(l) + 1e-6f);
      p += pr * bro[rr][v];
    }
  };
  int tt = t0;
  for (; tt + 2 <= t1; tt += 2) { body(tt); body(tt + 1); }
  if (tt < t1) body(tt);
  #pragma unroll
  for (int off = 1; off < 64; off <<= 1) p += __shfl_xor(p, off, 64);
  if (lane == 0) atomicAdd(out, -p * (1.0f / (float)B_));
}

// ---------------------------------------------------------------------------
extern "C" void kernel_launch(void* const* d_in, const int* in_sizes, int n_in,
                              void* d_out, int out_size, void* d_ws, size_t ws_size,
                              hipStream_t stream)
{
  const float* bows    = (const float*)d_in[0];
  const float* nb      = (const float*)d_in[1];
  const float* labels  = (const float*)d_in[2];
  const float* W1      = (const float*)d_in[3];
  const float* b1      = (const float*)d_in[4];
  const float* W2      = (const float*)d_in[5];
  const float* b2      = (const float*)d_in[6];
  const float* bn1_g   = (const float*)d_in[7];
  const float* bn1_b   = (const float*)d_in[8];
  const float* bn1_m   = (const float*)d_in[9];
  const float* bn1_v   = (const float*)d_in[10];
  const float* bn2_g   = (const float*)d_in[11];
  const float* bn2_b   = (const float*)d_in[12];
  const float* bn2_m   = (const float*)d_in[13];
  const float* bn2_v   = (const float*)d_in[14];
  const float* muW     = (const float*)d_in[15];
  const float* mub     = (const float*)d_in[16];
  const float* lsW     = (const float*)d_in[17];
  const float* lsb     = (const float*)d_in[18];
  const float* beta    = (const float*)d_in[19];
  const float* gamma   = (const float*)d_in[20];
  const float* brates  = (const float*)d_in[21];
  const float* bow_w   = (const float*)d_in[22];
  const float* bow_b   = (const float*)d_in[23];
  const float* topic_w = (const float*)d_in[24];
  const float* topic_b = (const float*)d_in[25];
  float* out = (float*)d_out;

  char* ws = (char*)d_ws;
  size_t off = 0;
  auto take = [&](size_t bytes) { void* p = ws + off; off = (off + bytes + 255) & ~(size_t)255; return p; };

  short* Wcat    = (short*)take((size_t)NW * VP * 2);        // 38.4 MB
  short* betab   = (short*)take((size_t)V_ * 64 * 2);        // 6.4 MB
  float* h1      = (float*)take((size_t)B_ * HP * 4);
  float* h2      = (float*)take((size_t)B_ * HP * 4);
  short* thetab  = (short*)take((size_t)B_ * KP * 2);
  float* thetaf  = (float*)take((size_t)B_ * KP * 4);
  float* hetmat  = (float*)take((size_t)B_ * KP * 4);
  float* accums  = (float*)take(4352);
  float* part1   = (float*)(ws + off);
  size_t remain = (ws_size > off) ? (ws_size - off) : 0;
  int S = (int)(remain / ((size_t)B_ * NW * 4));
  if (S > 42) S = 42;
  if (S < 1)  S = 1;
  const int sps = (NSTEP + S - 1) / S;

  hipMemsetAsync(accums, 0, 4352, stream);
  k_cvtW<<<(300 * (VP / 8) + 255) / 256, 256, 0, stream>>>(W1, Wcat);
  k_sb  <<<783, 256, 0, stream>>>(beta, gamma, brates, bow_w, Wcat, betab, accums);
  k_bg  <<<12 * S, 256, 0, stream>>>(nb, Wcat, part1, sps);
  k_red <<<(B_ * NW) / 256, 256, 0, stream>>>(part1, S, b1, bn1_g, bn1_b, bn1_m, bn1_v, h1, hetmat);
  k_kb2 <<<B_, 320, 0, stream>>>(h1, W2, b2, bn2_g, bn2_b, bn2_m, bn2_v, h2);
  k_kb3 <<<B_, 64, 0, stream>>>(h2, muW, mub, lsW, lsb, thetab, thetaf, accums + 1024);
  k_c1  <<<8 * 96, 256, 0, stream>>>(thetab, betab, brates, accums);
  k_d1  <<<1, 512, 0, stream>>>(accums, hetmat, thetaf, labels, topic_w, topic_b, bow_b, out);
  k_c2  <<<8 * 96, 256, 0, stream>>>(thetab, betab, brates, accums + 512, bows, out);
}

// Round 3
// 494.514 us; speedup vs baseline: 1.3676x; 1.3223x over previous
//
#include <hip/hip_runtime.h>
#include <hip/hip_bf16.h>
#include <math.h>

// ---------------------------------------------------------------------------
// HeterogeneousSupervisedTopicModel fwd: recon_loss, other_loss, kld_theta
// B=512, V=50000, K=50, H=300.
// Round 3: no atomics anywhere (partial buffers + deterministic reduce);
// prep kernels merged; MLP chain fused; n-fastest k_bg ordering for A reuse.
// ---------------------------------------------------------------------------

#define B_  512
#define V_  50000
#define VP  50016    // V padded to multiple of 32 (zero-filled in Wcat)
#define K_  50
#define H_  300
#define KP  64
#define NW  384      // Wcat rows: 0..299 W1, 320..369 beta*gamma, 370 bow_w
#define NSTEP 1563   // VP/32
#define NCVT 7327    // ceil(300*(VP/8)/256) blocks for the W1 convert part
#define NSB  782     // ceil(V/64) blocks for the beta/gamma part

typedef __attribute__((ext_vector_type(8))) short short8;
typedef __attribute__((ext_vector_type(4))) float f32x4;

static __device__ __forceinline__ short bf16s(float f) {
  unsigned int u = __builtin_bit_cast(unsigned int, f);
  u += 0x7fffu + ((u >> 16) & 1u);
  return (short)(u >> 16);
}

static __device__ __forceinline__ unsigned int pkbf(float lo, float hi) {
  __hip_bfloat162 t = __float22bfloat162_rn(float2{lo, hi});
  unsigned int u; __builtin_memcpy(&u, &t, 4); return u;
}

static __device__ __forceinline__ short8 to_bf8(float4 a, float4 b) {
  unsigned int u[4];
  u[0] = pkbf(a.x, a.y); u[1] = pkbf(a.z, a.w);
  u[2] = pkbf(b.x, b.y); u[3] = pkbf(b.z, b.w);
  short8 r; __builtin_memcpy(&r, u, 16); return r;
}

// ---------------------------------------------------------------------------
// k_prep: blocks [0,NCVT): Wcat rows 0..299 = bf16(W1) (coalesced stream)
//         blocks [NCVT, NCVT+NSB): per-64-v tile:
//           Wcat rows 300..383 (320..369 = (beta*gamma)^T, 370 = bow_w, rest 0)
//           betab [V][64] bf16(beta) (cols 50..63 zero)
//           partials: pg[blk]=sum|gamma|, pbr[blk]=sum|br|, pbw2[blk]=sum bw^2
// ---------------------------------------------------------------------------
__global__ __launch_bounds__(256) void k_prep(
    const float* __restrict__ W1,
    const float* __restrict__ beta, const float* __restrict__ gamma,
    const float* __restrict__ br,   const float* __restrict__ bw,
    short* __restrict__ Wcat, short* __restrict__ betab,
    float* __restrict__ pg, float* __restrict__ pbr, float* __restrict__ pbw2)
{
  __shared__ short sbt[64 * 52];   // bf16(beta*gamma), [j][k] stride 52
  __shared__ short bbt[64 * 52];   // bf16(beta)
  __shared__ float redA[4];
  const int tid = threadIdx.x;

  if (blockIdx.x < NCVT) {
    const int idx = blockIdx.x * 256 + tid;          // < 300*6252
    if (idx >= 300 * (VP / 8)) return;
    const int r = idx / (VP / 8);
    const int c = (idx - r * (VP / 8)) * 8;
    short8 outv;
    if (c + 8 <= V_) {
      const float4* p = (const float4*)(W1 + (size_t)r * V_ + c);
      outv = to_bf8(p[0], p[1]);
    } else {
      outv = short8{0, 0, 0, 0, 0, 0, 0, 0};
    }
    *(short8*)(Wcat + (size_t)r * VP + c) = outv;
    return;
  }

  const int blk = blockIdx.x - NCVT;                 // 0..781
  const int v0 = blk * 64;
  const int nvalid = (V_ - v0 < 64) ? (V_ - v0) : 64;
  const int nwrite = (VP - v0 < 64) ? (VP - v0) : 64;

  // vectorized load of beta/gamma tile; populate LDS bf16 tiles + gabs
  const int nf4 = (nvalid * 50) / 4;                 // 800 or 200, exact
  const float4* bsrc = (const float4*)(beta  + (size_t)v0 * 50);
  const float4* gsrc = (const float4*)(gamma + (size_t)v0 * 50);
  float gabs = 0.f;
  for (int f = tid; f < nf4; f += 256) {
    float4 bv = bsrc[f];
    float4 gv = gsrc[f];
    float be[4] = {bv.x, bv.y, bv.z, bv.w};
    float ge[4] = {gv.x, gv.y, gv.z, gv.w};
    #pragma unroll
    for (int e = 0; e < 4; ++e) {
      int idx = f * 4 + e;
      int j = idx / 50, k = idx - j * 50;
      gabs += fabsf(ge[e]);
      bbt[j * 52 + k] = bf16s(be[e]);
      sbt[j * 52 + k] = bf16s(be[e] * ge[e]);
    }
  }
  // block-reduce gabs -> pg[blk]
  #pragma unroll
  for (int off = 1; off < 64; off <<= 1) gabs += __shfl_xor(gabs, off, 64);
  if ((tid & 63) == 0) redA[tid >> 6] = gabs;
  // wave 0: per-block br / bw^2 partials
  if (tid < 64) {
    float s1 = 0.f, s2 = 0.f;
    if (tid < nvalid) {
      s1 = fabsf(br[v0 + tid]);
      float w = bw[v0 + tid]; s2 = w * w;
    }
    #pragma unroll
    for (int off = 1; off < 64; off <<= 1) {
      s1 += __shfl_xor(s1, off, 64);
      s2 += __shfl_xor(s2, off, 64);
    }
    if (tid == 0) { pbr[blk] = s1; pbw2[blk] = s2; }
  }
  __syncthreads();
  if (tid == 0) pg[blk] = redA[0] + redA[1] + redA[2] + redA[3];

  const int j = tid & 63;
  const int q = tid >> 6;
  // Wcat rows 300..383 (transposed scatter from LDS)
  #pragma unroll
  for (int p = 0; p < 21; ++p) {
    const int kk = p * 4 + q;          // 0..83
    if (j < nwrite) {
      short val = 0;
      if (j < nvalid) {
        if (kk >= 20 && kk < 70)      val = sbt[j * 52 + (kk - 20)];
        else if (kk == 70)            val = bf16s(bw[v0 + j]);
      }
      Wcat[(size_t)(300 + kk) * VP + v0 + j] = val;
    }
  }
  // betab rows (vectorized out of LDS via register repack)
  if (j < nvalid) {
    __attribute__((aligned(16))) short tmp[16];
    #pragma unroll
    for (int t = 0; t < 16; ++t) {
      int k = q * 16 + t;
      tmp[t] = (k < K_) ? bbt[j * 52 + k] : (short)0;
    }
    short8* dst = (short8*)(betab + (size_t)(v0 + j) * 64 + q * 16);
    dst[0] = *(const short8*)&tmp[0];
    dst[1] = *(const short8*)&tmp[8];
  }
}

// ---------------------------------------------------------------------------
// k_bg: part[s][512][384] = slab-partial of nb(fp32) @ Wcat^T(bf16).
// Block = 4 waves (2m x 2n), block tile 128x128, wave tile 64x64.
// Register double-buffer; n varies fastest across blocks (A-slab L2/L3 reuse).
// ---------------------------------------------------------------------------
__global__ __launch_bounds__(256, 2) void k_bg(
    const float* __restrict__ A, const short* __restrict__ Wcat,
    float* __restrict__ part, int sps)
{
  const int t = blockIdx.x;
  const int s = t / 12;
  const int r = t % 12;
  const int bni = r % 3, bmi = r / 3;      // n fastest: adjacent blocks share A
  const int lane = threadIdx.x & 63, wv = threadIdx.x >> 6;
  const int l15 = lane & 15, quad = lane >> 4;
  const int m0 = bmi * 128 + (wv & 1) * 64;
  const int n0 = bni * 128 + (wv >> 1) * 64;
  int st0 = s * sps;
  int st1 = st0 + sps; if (st1 > NSTEP) st1 = NSTEP;

  const float* ap[4]; const short* bp[4];
  #pragma unroll
  for (int i = 0; i < 4; ++i) ap[i] = A + (size_t)(m0 + 16 * i + l15) * V_;
  #pragma unroll
  for (int jj = 0; jj < 4; ++jj) bp[jj] = Wcat + (size_t)(n0 + 16 * jj + l15) * VP;

  f32x4 acc[4][4];
  #pragma unroll
  for (int i = 0; i < 4; ++i)
    #pragma unroll
    for (int jj = 0; jj < 4; ++jj) acc[i][jj] = f32x4{0.f, 0.f, 0.f, 0.f};

  float4 A0[4][2], A1[4][2];
  short8 B0[4], B1[4];

  auto ld = [&](int st, float4 (&Ar)[4][2], short8 (&Br)[4]) {
    const int kk = st * 32 + quad * 8;
    if (st != 1562) {
      #pragma unroll
      for (int i = 0; i < 4; ++i) {
        const float4* p = (const float4*)(ap[i] + kk);
        Ar[i][0] = p[0]; Ar[i][1] = p[1];
      }
    } else {
      const float4 z{0.f, 0.f, 0.f, 0.f};
      #pragma unroll
      for (int i = 0; i < 4; ++i) {
        if (quad < 2) {
          const float4* p = (const float4*)(ap[i] + kk);
          Ar[i][0] = p[0]; Ar[i][1] = p[1];
        } else { Ar[i][0] = z; Ar[i][1] = z; }
      }
    }
    #pragma unroll
    for (int jj = 0; jj < 4; ++jj) Br[jj] = *(const short8*)(bp[jj] + kk);
  };
  auto comp = [&](float4 (&Ar)[4][2], short8 (&Br)[4]) {
    short8 af[4];
    #pragma unroll
    for (int i = 0; i < 4; ++i) af[i] = to_bf8(Ar[i][0], Ar[i][1]);
    #pragma unroll
    for (int i = 0; i < 4; ++i)
      #pragma unroll
      for (int jj = 0; jj < 4; ++jj)
        acc[i][jj] = __builtin_amdgcn_mfma_f32_16x16x32_bf16(af[i], Br[jj], acc[i][jj], 0, 0, 0);
  };

  if (st0 < st1) {
    ld(st0, A0, B0);
    int st = st0;
    for (; st + 2 <= st1; st += 2) {
      ld(st + 1, A1, B1);
      comp(A0, B0);
      if (st + 2 < st1) ld(st + 2, A0, B0);
      comp(A1, B1);
    }
    if (st < st1) comp(A0, B0);
  }
  float* op = part + (size_t)s * (B_ * NW);
  #pragma unroll
  for (int i = 0; i < 4; ++i)
    #pragma unroll
    for (int jj = 0; jj < 4; ++jj)
      #pragma unroll
      for (int rr = 0; rr < 4; ++rr)
        op[(size_t)(m0 + 16 * i + quad * 4 + rr) * NW + (n0 + 16 * jj + l15)] = acc[i][jj][rr];
}

// ---------------------------------------------------------------------------
// k_mlp: one block per batch row b (320 threads):
//   slab-reduce -> bias/relu/BN1 -> h1 (LDS); hetmat row;
//   W2 GEMV -> relu/BN2 -> h2 (LDS); mu/ls GEMVs; softmax -> theta; kld partial
// ---------------------------------------------------------------------------
__global__ __launch_bounds__(320) void k_mlp(
    const float* __restrict__ part, int S,
    const float* __restrict__ b1,
    const float* __restrict__ g1, const float* __restrict__ bb1,
    const float* __restrict__ m1, const float* __restrict__ v1,
    const float* __restrict__ W2, const float* __restrict__ b2,
    const float* __restrict__ g2, const float* __restrict__ bb2,
    const float* __restrict__ m2, const float* __restrict__ v2,
    const float* __restrict__ muW, const float* __restrict__ mub,
    const float* __restrict__ lsW, const float* __restrict__ lsb,
    short* __restrict__ thetab, float* __restrict__ thetaf,
    float* __restrict__ hetmat, float* __restrict__ kldp)
{
  __shared__ __attribute__((aligned(16))) float h1s[H_];
  __shared__ __attribute__((aligned(16))) float h2s[H_];
  const int b = blockIdx.x;
  const int tid = threadIdx.x;
  const float* pb = part + (size_t)b * NW;

  if (tid < H_) {
    float s0 = 0.f, s1 = 0.f, s2 = 0.f, s3 = 0.f;
    int i = 0;
    for (; i + 4 <= S; i += 4) {
      s0 += pb[(size_t)(i + 0) * (B_ * NW) + tid];
      s1 += pb[(size_t)(i + 1) * (B_ * NW) + tid];
      s2 += pb[(size_t)(i + 2) * (B_ * NW) + tid];
      s3 += pb[(size_t)(i + 3) * (B_ * NW) + tid];
    }
    for (; i < S; ++i) s0 += pb[(size_t)i * (B_ * NW) + tid];
    float s = (s0 + s1) + (s2 + s3);
    float x = fmaxf(s + b1[tid], 0.f);
    h1s[tid] = (x - m1[tid]) * rsqrtf(v1[tid] + 1e-5f) * g1[tid] + bb1[tid];
  }
  if (tid < 51) {
    float s0 = 0.f, s1 = 0.f;
    int i = 0;
    for (; i + 2 <= S; i += 2) {
      s0 += pb[(size_t)(i + 0) * (B_ * NW) + 320 + tid];
      s1 += pb[(size_t)(i + 1) * (B_ * NW) + 320 + tid];
    }
    for (; i < S; ++i) s0 += pb[(size_t)i * (B_ * NW) + 320 + tid];
    hetmat[(size_t)b * KP + tid] = s0 + s1;
  }
  __syncthreads();
  if (tid < H_) {
    const float4* wr = (const float4*)(W2 + (size_t)tid * H_);
    const float4* hr = (const float4*)h1s;
    float acc = 0.f;
    for (int q = 0; q < H_ / 4; ++q) {
      float4 w = wr[q], h = hr[q];
      acc += w.x * h.x + w.y * h.y + w.z * h.z + w.w * h.w;
    }
    float x = fmaxf(acc + b2[tid], 0.f);
    h2s[tid] = (x - m2[tid]) * rsqrtf(v2[tid] + 1e-5f) * g2[tid] + bb2[tid];
  }
  __syncthreads();
  if (tid < 64) {
    float mu = 0.f, ls = 0.f;
    if (tid < K_) {
      const float4* mr = (const float4*)(muW + (size_t)tid * H_);
      const float4* lr = (const float4*)(lsW + (size_t)tid * H_);
      const float4* hr = (const float4*)h2s;
      for (int q = 0; q < H_ / 4; ++q) {
        float4 h = hr[q], a = mr[q], c = lr[q];
        mu += a.x * h.x + a.y * h.y + a.z * h.z + a.w * h.w;
        ls += c.x * h.x + c.y * h.y + c.z * h.z + c.w * h.w;
      }
      mu += mub[tid]; ls += lsb[tid];
    }
    float term = (tid < K_) ? (1.f + ls - mu * mu - __expf(ls)) : 0.f;
    float ts = term;
    #pragma unroll
    for (int off = 1; off < 64; off <<= 1) ts += __shfl_xor(ts, off, 64);
    if (tid == 0) kldp[b] = ts;
    float mv = (tid < K_) ? mu : -INFINITY;
    #pragma unroll
    for (int off = 1; off < 64; off <<= 1) mv = fmaxf(mv, __shfl_xor(mv, off, 64));
    float e = (tid < K_) ? __expf(mu - mv) : 0.f;
    float se = e;
    #pragma unroll
    for (int off = 1; off < 64; off <<= 1) se += __shfl_xor(se, off, 64);
    float tv = (tid < K_) ? (e / se) : 0.f;
    thetaf[(size_t)b * KP + tid] = tv;
    thetab[(size_t)b * KP + tid] = bf16s(tv);
  }
}

// ---------------------------------------------------------------------------
// k_c1: c1p[vs][b] = partial sum_v exp(theta[b].beta[v] + br[v]) for slice vs
// ---------------------------------------------------------------------------
__global__ __launch_bounds__(256, 2) void k_c1(
    const short* __restrict__ thetab, const short* __restrict__ betab,
    const float* __restrict__ br, float* __restrict__ c1p)
{
  const int blk = blockIdx.x;
  const int bm = blk & 7, vs = blk >> 3;
  const int lane = threadIdx.x & 63, wv = threadIdx.x >> 6;
  const int l15 = lane & 15, quad = lane >> 4;
  const int b0 = bm * 64 + wv * 16;
  const short8* arow = (const short8*)(thetab + (size_t)(b0 + l15) * KP);
  const short8 a0 = arow[quad], a1 = arow[4 + quad];
  int t0 = vs * 33, t1 = t0 + 33; if (t1 > 3125) t1 = 3125;
  float p0 = 0.f, p1 = 0.f, p2 = 0.f, p3 = 0.f;
  auto body = [&](int tt) {
    const int v0 = tt * 16;
    const short8* brow = (const short8*)(betab + (size_t)(v0 + l15) * KP);
    short8 q0 = brow[quad], q1 = brow[4 + quad];
    f32x4 acc = {0.f, 0.f, 0.f, 0.f};
    acc = __builtin_amdgcn_mfma_f32_16x16x32_bf16(a0, q0, acc, 0, 0, 0);
    acc = __builtin_amdgcn_mfma_f32_16x16x32_bf16(a1, q1, acc, 0, 0, 0);
    const float brv = br[v0 + l15];
    p0 += __expf(acc[0] + brv);
    p1 += __expf(acc[1] + brv);
    p2 += __expf(acc[2] + brv);
    p3 += __expf(acc[3] + brv);
  };
  int tt = t0;
  for (; tt + 2 <= t1; tt += 2) { body(tt); body(tt + 1); }
  if (tt < t1) body(tt);
  #pragma unroll
  for (int off = 1; off < 16; off <<= 1) {
    p0 += __shfl_xor(p0, off, 16);
    p1 += __shfl_xor(p1, off, 16);
    p2 += __shfl_xor(p2, off, 16);
    p3 += __shfl_xor(p3, off, 16);
  }
  if (l15 == 0) {
    float* dst = c1p + (size_t)vs * B_ + b0 + quad * 4;
    dst[0] = p0; dst[1] = p1; dst[2] = p2; dst[3] = p3;
  }
}

// ---------------------------------------------------------------------------
// k_d1: lse; expected_pred + mse; reduce all partial arrays; out[1], out[2]
// ---------------------------------------------------------------------------
static __device__ __forceinline__ float blockred512(float x, float* red) {
  #pragma unroll
  for (int off = 1; off < 64; off <<= 1) x += __shfl_xor(x, off, 64);
  if ((threadIdx.x & 63) == 0) red[threadIdx.x >> 6] = x;
  __syncthreads();
  float r = 0.f;
  if (threadIdx.x == 0)
    for (int i = 0; i < 8; ++i) r += red[i];
  __syncthreads();
  return r;
}

__global__ __launch_bounds__(512) void k_d1(
    const float* __restrict__ c1p, const float* __restrict__ kldp,
    const float* __restrict__ pg, const float* __restrict__ pbr,
    const float* __restrict__ pbw2,
    const float* __restrict__ hetmat, const float* __restrict__ thetaf,
    const float* __restrict__ labels, const float* __restrict__ topic_w,
    const float* __restrict__ topic_b, const float* __restrict__ bow_b,
    float* __restrict__ lseb, float* __restrict__ out)
{
  __shared__ float red[8];
  const int b = threadIdx.x;
  float se = 0.f;
  for (int i = 0; i < 96; ++i) se += c1p[(size_t)i * B_ + b];
  lseb[b] = __logf(se);
  float het = 0.f, tpc = 0.f;
  #pragma unroll
  for (int k = 0; k < K_; ++k) {
    float th = thetaf[(size_t)b * KP + k];
    het += th * hetmat[(size_t)b * KP + k];
    tpc += th * topic_w[k];
  }
  float ep = het + hetmat[(size_t)b * KP + 50] + bow_b[0] + tpc + topic_b[0];
  float d = ep - labels[b];
  float mse  = blockred512(d * d, red);
  float kl   = blockred512(kldp[b], red);
  float sg = 0.f, sr = 0.f, sw = 0.f;
  for (int i = b; i < NSB; i += 512) { sg += pg[i]; sr += pbr[i]; sw += pbw2[i]; }
  sg = blockred512(sg, red);
  sr = blockred512(sr, red);
  sw = blockred512(sw, red);
  if (b == 0) {
    out[1] = 0.0005f * sr + mse / (float)B_ + 5e-6f * sg + 0.0005f * sqrtf(sw);
    out[2] = -0.5f * kl / (float)B_;
  }
}

// ---------------------------------------------------------------------------
// k_c2: c2p[blk] = partial of sum_bv log(exp(logit-lse)+1e-6)*bows
// ---------------------------------------------------------------------------
__global__ __launch_bounds__(256, 2) void k_c2(
    const short* __restrict__ thetab, const short* __restrict__ betab,
    const float* __restrict__ br, const float* __restrict__ lseb,
    const float* __restrict__ bows, float* __restrict__ c2p)
{
  __shared__ float red[4];
  const int blk = blockIdx.x;
  const int bm = blk & 7, vs = blk >> 3;
  const int lane = threadIdx.x & 63, wv = threadIdx.x >> 6;
  const int l15 = lane & 15, quad = lane >> 4;
  const int b0 = bm * 64 + wv * 16;
  const short8* arow = (const short8*)(thetab + (size_t)(b0 + l15) * KP);
  const short8 a0 = arow[quad], a1 = arow[4 + quad];
  float lse4[4]; const float* bro[4];
  #pragma unroll
  for (int rr = 0; rr < 4; ++rr) {
    lse4[rr] = lseb[b0 + quad * 4 + rr];
    bro[rr] = bows + (size_t)(b0 + quad * 4 + rr) * V_;
  }
  int t0 = vs * 33, t1 = t0 + 33; if (t1 > 3125) t1 = 3125;
  float p = 0.f;
  auto body = [&](int tt) {
    const int v0 = tt * 16;
    const int v = v0 + l15;
    const short8* brow = (const short8*)(betab + (size_t)v * KP);
    short8 q0 = brow[quad], q1 = brow[4 + quad];
    f32x4 acc = {0.f, 0.f, 0.f, 0.f};
    acc = __builtin_amdgcn_mfma_f32_16x16x32_bf16(a0, q0, acc, 0, 0, 0);
    acc = __builtin_amdgcn_mfma_f32_16x16x32_bf16(a1, q1, acc, 0, 0, 0);
    const float brv = br[v];
    #pragma unroll
    for (int rr = 0; rr < 4; ++rr) {
      float l = acc[rr] + brv - lse4[rr];
      float pr = __logf(__expf(l) + 1e-6f);
      p += pr * bro[rr][v];
    }
  };
  int tt = t0;
  for (; tt + 2 <= t1; tt += 2) { body(tt); body(tt + 1); }
  if (tt < t1) body(tt);
  #pragma unroll
  for (int off = 1; off < 64; off <<= 1) p += __shfl_xor(p, off, 64);
  if (lane == 0) red[wv] = p;
  __syncthreads();
  if (threadIdx.x == 0) c2p[blk] = red[0] + red[1] + red[2] + red[3];
}

// k_d2: out[0] = -sum(c2p)/B
__global__ __launch_bounds__(256) void k_d2(
    const float* __restrict__ c2p, float* __restrict__ out)
{
  __shared__ float red[4];
  float s = 0.f;
  for (int i = threadIdx.x; i < 768; i += 256) s += c2p[i];
  #pragma unroll
  for (int off = 1; off < 64; off <<= 1) s += __shfl_xor(s, off, 64);
  if ((threadIdx.x & 63) == 0) red[threadIdx.x >> 6] = s;
  __syncthreads();
  if (threadIdx.x == 0)
    out[0] = -(red[0] + red[1] + red[2] + red[3]) / (float)B_;
}

// ---------------------------------------------------------------------------
extern "C" void kernel_launch(void* const* d_in, const int* in_sizes, int n_in,
                              void* d_out, int out_size, void* d_ws, size_t ws_size,
                              hipStream_t stream)
{
  const float* bows    = (const float*)d_in[0];
  const float* nb      = (const float*)d_in[1];
  const float* labels  = (const float*)d_in[2];
  const float* W1      = (const float*)d_in[3];
  const float* b1      = (const float*)d_in[4];
  const float* W2      = (const float*)d_in[5];
  const float* b2      = (const float*)d_in[6];
  const float* bn1_g   = (const float*)d_in[7];
  const float* bn1_b   = (const float*)d_in[8];
  const float* bn1_m   = (const float*)d_in[9];
  const float* bn1_v   = (const float*)d_in[10];
  const float* bn2_g   = (const float*)d_in[11];
  const float* bn2_b   = (const float*)d_in[12];
  const float* bn2_m   = (const float*)d_in[13];
  const float* bn2_v   = (const float*)d_in[14];
  const float* muW     = (const float*)d_in[15];
  const float* mub     = (const float*)d_in[16];
  const float* lsW     = (const float*)d_in[17];
  const float* lsb     = (const float*)d_in[18];
  const float* beta    = (const float*)d_in[19];
  const float* gamma   = (const float*)d_in[20];
  const float* brates  = (const float*)d_in[21];
  const float* bow_w   = (const float*)d_in[22];
  const float* bow_b   = (const float*)d_in[23];
  const float* topic_w = (const float*)d_in[24];
  const float* topic_b = (const float*)d_in[25];
  float* out = (float*)d_out;

  char* ws = (char*)d_ws;
  size_t off = 0;
  auto take = [&](size_t bytes) { void* p = ws + off; off = (off + bytes + 255) & ~(size_t)255; return p; };

  short* Wcat    = (short*)take((size_t)NW * VP * 2);        // 38.4 MB
  short* betab   = (short*)take((size_t)V_ * 64 * 2);        // 6.4 MB
  short* thetab  = (short*)take((size_t)B_ * KP * 2);
  float* thetaf  = (float*)take((size_t)B_ * KP * 4);
  float* hetmat  = (float*)take((size_t)B_ * KP * 4);
  float* kldp    = (float*)take((size_t)B_ * 4);
  float* c1p     = (float*)take((size_t)96 * B_ * 4);
  float* c2p     = (float*)take((size_t)768 * 4);
  float* lse_    = (float*)take((size_t)B_ * 4);
  float* pg      = (float*)take((size_t)NSB * 4);
  float* pbr     = (float*)take((size_t)NSB * 4);
  float* pbw2    = (float*)take((size_t)NSB * 4);
  float* part1   = (float*)(ws + off);
  size_t remain = (ws_size > off) ? (ws_size - off) : 0;
  int S = (int)(remain / ((size_t)B_ * NW * 4));
  if (S > 42) S = 42;
  if (S < 1)  S = 1;
  const int sps = (NSTEP + S - 1) / S;

  k_prep<<<NCVT + NSB, 256, 0, stream>>>(W1, beta, gamma, brates, bow_w,
                                         Wcat, betab, pg, pbr, pbw2);
  k_bg  <<<12 * S, 256, 0, stream>>>(nb, Wcat, part1, sps);
  k_mlp <<<B_, 320, 0, stream>>>(part1, S, b1, bn1_g, bn1_b, bn1_m, bn1_v,
                                 W2, b2, bn2_g, bn2_b, bn2_m, bn2_v,
                                 muW, mub, lsW, lsb, thetab, thetaf, hetmat, kldp);
  k_c1  <<<8 * 96, 256, 0, stream>>>(thetab, betab, brates, c1p);
  k_d1  <<<1, 512, 0, stream>>>(c1p, kldp, pg, pbr, pbw2, hetmat, thetaf,
                                labels, topic_w, topic_b, bow_b, lse_, out);
  k_c2  <<<8 * 96, 256, 0, stream>>>(thetab, betab, brates, lse_, bows, c2p);
  k_d2  <<<1, 256, 0, stream>>>(c2p, out);
}

// Round 4
// 479.180 us; speedup vs baseline: 1.4113x; 1.0320x over previous
//
#include <hip/hip_runtime.h>
#include <hip/hip_bf16.h>
#include <math.h>

// ---------------------------------------------------------------------------
// HeterogeneousSupervisedTopicModel fwd: recon_loss, other_loss, kld_theta
// B=512, V=50000, K=50, H=300.
// Round 4: bf16 K-tile-major operands for the big GEMM.
//   nbb  [st][512][32] bf16   (nb converted, zero-padded to VP)
//   Wcatb[st][384][32] bf16   (rows 0..299 W1, 320..369 beta*gamma, 370 bow_w)
// k_bg inner loop: 8 contiguous 16B loads + 16 MFMA, no cvt, no tail.
// ---------------------------------------------------------------------------

#define B_  512
#define V_  50000
#define VP  50016    // V padded to multiple of 32
#define K_  50
#define H_  300
#define KP  64
#define NW  384
#define NSTEP 1563   // VP/32
#define NCVT 7327    // ceil(NSTEP*300*4 / 256)  W1-convert blocks
#define NSB  782     // ceil(V/64)               beta/gamma blocks
#define NACV 12504   // NSTEP*512*4 / 256        nb-convert blocks (exact)

typedef __attribute__((ext_vector_type(8))) short short8;
typedef __attribute__((ext_vector_type(4))) float f32x4;

static __device__ __forceinline__ short bf16s(float f) {
  unsigned int u = __builtin_bit_cast(unsigned int, f);
  u += 0x7fffu + ((u >> 16) & 1u);
  return (short)(u >> 16);
}

static __device__ __forceinline__ unsigned int pkbf(float lo, float hi) {
  __hip_bfloat162 t = __float22bfloat162_rn(float2{lo, hi});
  unsigned int u; __builtin_memcpy(&u, &t, 4); return u;
}

static __device__ __forceinline__ short8 to_bf8(float4 a, float4 b) {
  unsigned int u[4];
  u[0] = pkbf(a.x, a.y); u[1] = pkbf(a.z, a.w);
  u[2] = pkbf(b.x, b.y); u[3] = pkbf(b.z, b.w);
  short8 r; __builtin_memcpy(&r, u, 16); return r;
}

// ---------------------------------------------------------------------------
// k_prep, three block ranges in one launch:
//  [0, NCVT)            : Wcatb rows 0..299 = bf16(W1), K-tile-major
//  [NCVT, NCVT+NSB)     : per 64-v tile: Wcatb rows 300..383 (320..369 =
//                         (beta*gamma)^T, 370 = bow_w, rest 0); betab[V][64];
//                         partials pg/pbr/pbw2
//  [NCVT+NSB, +NACV)    : nbb = bf16(nb), K-tile-major, zero-padded
// ---------------------------------------------------------------------------
__global__ __launch_bounds__(256) void k_prep(
    const float* __restrict__ W1,
    const float* __restrict__ beta, const float* __restrict__ gamma,
    const float* __restrict__ br,   const float* __restrict__ bw,
    const float* __restrict__ nb,
    short* __restrict__ Wcatb, short* __restrict__ betab,
    short* __restrict__ nbb,
    float* __restrict__ pg, float* __restrict__ pbr, float* __restrict__ pbw2)
{
  __shared__ short sbt[64 * 52];
  __shared__ short bbt[64 * 52];
  __shared__ float redA[4];
  const int tid = threadIdx.x;
  const short8 z8 = {0, 0, 0, 0, 0, 0, 0, 0};

  if (blockIdx.x < NCVT) {
    // ---- W1 convert: thread covers (st, n, kq) -> 8 elements ----
    const int idx = blockIdx.x * 256 + tid;
    if (idx >= NSTEP * 300 * 4) return;
    const int st = idx / 1200;
    const int rem = idx - st * 1200;
    const int n = rem >> 2, kq = rem & 3;
    const int kbase = st * 32 + kq * 8;
    short8 o = z8;
    if (kbase + 8 <= V_) {
      const float4* p = (const float4*)(W1 + (size_t)n * V_ + kbase);
      o = to_bf8(p[0], p[1]);
    }
    *(short8*)(Wcatb + (size_t)st * 12288 + n * 32 + kq * 8) = o;
    return;
  }

  if (blockIdx.x >= NCVT + NSB) {
    // ---- nb convert: thread covers (st, r, kq) -> 8 elements ----
    const int idx = (blockIdx.x - (NCVT + NSB)) * 256 + tid;   // < NSTEP*2048
    const int st = idx >> 11;
    const int r  = (idx >> 2) & 511;
    const int kq = idx & 3;
    const int kbase = st * 32 + kq * 8;
    short8 o = z8;
    if (kbase + 8 <= V_) {
      const float4* p = (const float4*)(nb + (size_t)r * V_ + kbase);
      o = to_bf8(p[0], p[1]);
    }
    *(short8*)(nbb + (size_t)st * 16384 + r * 32 + kq * 8) = o;
    return;
  }

  // ---- beta/gamma tile ----
  const int blk = blockIdx.x - NCVT;                 // 0..781
  const int v0 = blk * 64;
  const int nvalid = (V_ - v0 < 64) ? (V_ - v0) : 64;
  const int nwrite = (VP - v0 < 64) ? (VP - v0) : 64;

  const int nf4 = (nvalid * 50) / 4;
  const float4* bsrc = (const float4*)(beta  + (size_t)v0 * 50);
  const float4* gsrc = (const float4*)(gamma + (size_t)v0 * 50);
  float gabs = 0.f;
  for (int f = tid; f < nf4; f += 256) {
    float4 bv = bsrc[f];
    float4 gv = gsrc[f];
    float be[4] = {bv.x, bv.y, bv.z, bv.w};
    float ge[4] = {gv.x, gv.y, gv.z, gv.w};
    #pragma unroll
    for (int e = 0; e < 4; ++e) {
      int idx = f * 4 + e;
      int j = idx / 50, k = idx - j * 50;
      gabs += fabsf(ge[e]);
      bbt[j * 52 + k] = bf16s(be[e]);
      sbt[j * 52 + k] = bf16s(be[e] * ge[e]);
    }
  }
  #pragma unroll
  for (int off = 1; off < 64; off <<= 1) gabs += __shfl_xor(gabs, off, 64);
  if ((tid & 63) == 0) redA[tid >> 6] = gabs;
  if (tid < 64) {
    float s1 = 0.f, s2 = 0.f;
    if (tid < nvalid) {
      s1 = fabsf(br[v0 + tid]);
      float w = bw[v0 + tid]; s2 = w * w;
    }
    #pragma unroll
    for (int off = 1; off < 64; off <<= 1) {
      s1 += __shfl_xor(s1, off, 64);
      s2 += __shfl_xor(s2, off, 64);
    }
    if (tid == 0) { pbr[blk] = s1; pbw2[blk] = s2; }
  }
  __syncthreads();
  if (tid == 0) pg[blk] = redA[0] + redA[1] + redA[2] + redA[3];

  const int j = tid & 63;
  const int q = tid >> 6;
  // Wcatb rows 300..383, this tile's 2 st-chunks (st = blk*2 + j/32)
  #pragma unroll
  for (int p = 0; p < 21; ++p) {
    const int kk = p * 4 + q;          // 0..83
    if (j < nwrite) {
      short val = 0;
      if (j < nvalid) {
        if (kk >= 20 && kk < 70)      val = sbt[j * 52 + (kk - 20)];
        else if (kk == 70)            val = bf16s(bw[v0 + j]);
      }
      Wcatb[(size_t)(blk * 2 + (j >> 5)) * 12288 + (300 + kk) * 32 + (j & 31)] = val;
    }
  }
  // betab rows
  if (j < nvalid) {
    __attribute__((aligned(16))) short tmp[16];
    #pragma unroll
    for (int t = 0; t < 16; ++t) {
      int k = q * 16 + t;
      tmp[t] = (k < K_) ? bbt[j * 52 + k] : (short)0;
    }
    short8* dst = (short8*)(betab + (size_t)(v0 + j) * 64 + q * 16);
    dst[0] = *(const short8*)&tmp[0];
    dst[1] = *(const short8*)&tmp[8];
  }
}

// ---------------------------------------------------------------------------
// k_bg: part[s][512][384] = slab-partial of nbb @ Wcatb^T (both bf16,
// K-tile-major).  Inner loop: 8 contiguous 16B loads + 16 MFMA, no cvt.
// Register double-buffer.  grid = 12 * S, 3 blocks/CU.
// ---------------------------------------------------------------------------
__global__ __launch_bounds__(256, 3) void k_bg(
    const short* __restrict__ Ab, const short* __restrict__ Bb,
    float* __restrict__ part, int sps)
{
  const int t = blockIdx.x;
  const int s = t / 12;
  const int r = t % 12;
  const int bni = r % 3, bmi = r / 3;
  const int lane = threadIdx.x & 63, wv = threadIdx.x >> 6;
  const int l15 = lane & 15, quad = lane >> 4;
  const int m0 = bmi * 128 + (wv & 1) * 64;
  const int n0 = bni * 128 + (wv >> 1) * 64;
  int st0 = s * sps, st1 = st0 + sps;
  if (st0 > NSTEP) st0 = NSTEP;
  if (st1 > NSTEP) st1 = NSTEP;
  const int nst = st1 - st0;

  const short8* pa = (const short8*)Ab + (size_t)st0 * 2048 + (m0 + l15) * 4 + quad;
  const short8* pb = (const short8*)Bb + (size_t)st0 * 1536 + (n0 + l15) * 4 + quad;

  f32x4 acc[4][4];
  #pragma unroll
  for (int i = 0; i < 4; ++i)
    #pragma unroll
    for (int jj = 0; jj < 4; ++jj) acc[i][jj] = f32x4{0.f, 0.f, 0.f, 0.f};

  short8 A0[4], A1[4], B0[4], B1[4];

  auto ld = [&](short8 (&Af)[4], short8 (&Bf)[4]) {
    #pragma unroll
    for (int i = 0; i < 4; ++i) Af[i] = pa[i * 64];
    #pragma unroll
    for (int jj = 0; jj < 4; ++jj) Bf[jj] = pb[jj * 64];
    pa += 2048; pb += 1536;
  };
  auto comp = [&](short8 (&Af)[4], short8 (&Bf)[4]) {
    #pragma unroll
    for (int i = 0; i < 4; ++i)
      #pragma unroll
      for (int jj = 0; jj < 4; ++jj)
        acc[i][jj] = __builtin_amdgcn_mfma_f32_16x16x32_bf16(Af[i], Bf[jj], acc[i][jj], 0, 0, 0);
  };

  if (nst > 0) {
    ld(A0, B0);
    int k = 0;
    for (; k + 2 <= nst; k += 2) {
      ld(A1, B1);                      // step k+1 (valid: k+1 < nst)
      comp(A0, B0);                    // step k
      if (k + 2 < nst) ld(A0, B0);     // step k+2
      comp(A1, B1);                    // step k+1
    }
    if (k < nst) comp(A0, B0);         // odd tail
  }

  float* op = part + (size_t)s * (B_ * NW);
  #pragma unroll
  for (int i = 0; i < 4; ++i)
    #pragma unroll
    for (int jj = 0; jj < 4; ++jj)
      #pragma unroll
      for (int rr = 0; rr < 4; ++rr)
        op[(size_t)(m0 + 16 * i + quad * 4 + rr) * NW + (n0 + 16 * jj + l15)] = acc[i][jj][rr];
}

// ---------------------------------------------------------------------------
// k_mlp: one block per batch row b (320 threads):
//   slab-reduce -> bias/relu/BN1 -> h1 (LDS); hetmat row;
//   W2 GEMV -> relu/BN2 -> h2 (LDS); mu/ls GEMVs; softmax -> theta; kld partial
// ---------------------------------------------------------------------------
__global__ __launch_bounds__(320) void k_mlp(
    const float* __restrict__ part, int S,
    const float* __restrict__ b1,
    const float* __restrict__ g1, const float* __restrict__ bb1,
    const float* __restrict__ m1, const float* __restrict__ v1,
    const float* __restrict__ W2, const float* __restrict__ b2,
    const float* __restrict__ g2, const float* __restrict__ bb2,
    const float* __restrict__ m2, const float* __restrict__ v2,
    const float* __restrict__ muW, const float* __restrict__ mub,
    const float* __restrict__ lsW, const float* __restrict__ lsb,
    short* __restrict__ thetab, float* __restrict__ thetaf,
    float* __restrict__ hetmat, float* __restrict__ kldp)
{
  __shared__ __attribute__((aligned(16))) float h1s[H_];
  __shared__ __attribute__((aligned(16))) float h2s[H_];
  const int b = blockIdx.x;
  const int tid = threadIdx.x;
  const float* pb = part + (size_t)b * NW;

  if (tid < H_) {
    float s0 = 0.f, s1 = 0.f, s2 = 0.f, s3 = 0.f;
    int i = 0;
    for (; i + 4 <= S; i += 4) {
      s0 += pb[(size_t)(i + 0) * (B_ * NW) + tid];
      s1 += pb[(size_t)(i + 1) * (B_ * NW) + tid];
      s2 += pb[(size_t)(i + 2) * (B_ * NW) + tid];
      s3 += pb[(size_t)(i + 3) * (B_ * NW) + tid];
    }
    for (; i < S; ++i) s0 += pb[(size_t)i * (B_ * NW) + tid];
    float s = (s0 + s1) + (s2 + s3);
    float x = fmaxf(s + b1[tid], 0.f);
    h1s[tid] = (x - m1[tid]) * rsqrtf(v1[tid] + 1e-5f) * g1[tid] + bb1[tid];
  }
  if (tid < 51) {
    float s0 = 0.f, s1 = 0.f;
    int i = 0;
    for (; i + 2 <= S; i += 2) {
      s0 += pb[(size_t)(i + 0) * (B_ * NW) + 320 + tid];
      s1 += pb[(size_t)(i + 1) * (B_ * NW) + 320 + tid];
    }
    for (; i < S; ++i) s0 += pb[(size_t)i * (B_ * NW) + 320 + tid];
    hetmat[(size_t)b * KP + tid] = s0 + s1;
  }
  __syncthreads();
  if (tid < H_) {
    const float4* wr = (const float4*)(W2 + (size_t)tid * H_);
    const float4* hr = (const float4*)h1s;
    float acc = 0.f;
    for (int q = 0; q < H_ / 4; ++q) {
      float4 w = wr[q], h = hr[q];
      acc += w.x * h.x + w.y * h.y + w.z * h.z + w.w * h.w;
    }
    float x = fmaxf(acc + b2[tid], 0.f);
    h2s[tid] = (x - m2[tid]) * rsqrtf(v2[tid] + 1e-5f) * g2[tid] + bb2[tid];
  }
  __syncthreads();
  if (tid < 64) {
    float mu = 0.f, ls = 0.f;
    if (tid < K_) {
      const float4* mr = (const float4*)(muW + (size_t)tid * H_);
      const float4* lr = (const float4*)(lsW + (size_t)tid * H_);
      const float4* hr = (const float4*)h2s;
      for (int q = 0; q < H_ / 4; ++q) {
        float4 h = hr[q], a = mr[q], c = lr[q];
        mu += a.x * h.x + a.y * h.y + a.z * h.z + a.w * h.w;
        ls += c.x * h.x + c.y * h.y + c.z * h.z + c.w * h.w;
      }
      mu += mub[tid]; ls += lsb[tid];
    }
    float term = (tid < K_) ? (1.f + ls - mu * mu - __expf(ls)) : 0.f;
    float ts = term;
    #pragma unroll
    for (int off = 1; off < 64; off <<= 1) ts += __shfl_xor(ts, off, 64);
    if (tid == 0) kldp[b] = ts;
    float mv = (tid < K_) ? mu : -INFINITY;
    #pragma unroll
    for (int off = 1; off < 64; off <<= 1) mv = fmaxf(mv, __shfl_xor(mv, off, 64));
    float e = (tid < K_) ? __expf(mu - mv) : 0.f;
    float se = e;
    #pragma unroll
    for (int off = 1; off < 64; off <<= 1) se += __shfl_xor(se, off, 64);
    float tv = (tid < K_) ? (e / se) : 0.f;
    thetaf[(size_t)b * KP + tid] = tv;
    thetab[(size_t)b * KP + tid] = bf16s(tv);
  }
}

// ---------------------------------------------------------------------------
// k_c1: c1p[vs][b] = partial sum_v exp(theta[b].beta[v] + br[v])
// ---------------------------------------------------------------------------
__global__ __launch_bounds__(256, 2) void k_c1(
    const short* __restrict__ thetab, const short* __restrict__ betab,
    const float* __restrict__ br, float* __restrict__ c1p)
{
  const int blk = blockIdx.x;
  const int bm = blk & 7, vs = blk >> 3;
  const int lane = threadIdx.x & 63, wv = threadIdx.x >> 6;
  const int l15 = lane & 15, quad = lane >> 4;
  const int b0 = bm * 64 + wv * 16;
  const short8* arow = (const short8*)(thetab + (size_t)(b0 + l15) * KP);
  const short8 a0 = arow[quad], a1 = arow[4 + quad];
  int t0 = vs * 33, t1 = t0 + 33; if (t1 > 3125) t1 = 3125;
  float p0 = 0.f, p1 = 0.f, p2 = 0.f, p3 = 0.f;
  auto body = [&](int tt) {
    const int v0 = tt * 16;
    const short8* brow = (const short8*)(betab + (size_t)(v0 + l15) * KP);
    short8 q0 = brow[quad], q1 = brow[4 + quad];
    f32x4 acc = {0.f, 0.f, 0.f, 0.f};
    acc = __builtin_amdgcn_mfma_f32_16x16x32_bf16(a0, q0, acc, 0, 0, 0);
    acc = __builtin_amdgcn_mfma_f32_16x16x32_bf16(a1, q1, acc, 0, 0, 0);
    const float brv = br[v0 + l15];
    p0 += __expf(acc[0] + brv);
    p1 += __expf(acc[1] + brv);
    p2 += __expf(acc[2] + brv);
    p3 += __expf(acc[3] + brv);
  };
  int tt = t0;
  for (; tt + 2 <= t1; tt += 2) { body(tt); body(tt + 1); }
  if (tt < t1) body(tt);
  #pragma unroll
  for (int off = 1; off < 16; off <<= 1) {
    p0 += __shfl_xor(p0, off, 16);
    p1 += __shfl_xor(p1, off, 16);
    p2 += __shfl_xor(p2, off, 16);
    p3 += __shfl_xor(p3, off, 16);
  }
  if (l15 == 0) {
    float* dst = c1p + (size_t)vs * B_ + b0 + quad * 4;
    dst[0] = p0; dst[1] = p1; dst[2] = p2; dst[3] = p3;
  }
}

// ---------------------------------------------------------------------------
// k_d1: lse; expected_pred + mse; reduce partial arrays; out[1], out[2]
// ---------------------------------------------------------------------------
static __device__ __forceinline__ float blockred512(float x, float* red) {
  #pragma unroll
  for (int off = 1; off < 64; off <<= 1) x += __shfl_xor(x, off, 64);
  if ((threadIdx.x & 63) == 0) red[threadIdx.x >> 6] = x;
  __syncthreads();
  float r = 0.f;
  if (threadIdx.x == 0)
    for (int i = 0; i < 8; ++i) r += red[i];
  __syncthreads();
  return r;
}

__global__ __launch_bounds__(512) void k_d1(
    const float* __restrict__ c1p, const float* __restrict__ kldp,
    const float* __restrict__ pg, const float* __restrict__ pbr,
    const float* __restrict__ pbw2,
    const float* __restrict__ hetmat, const float* __restrict__ thetaf,
    const float* __restrict__ labels, const float* __restrict__ topic_w,
    const float* __restrict__ topic_b, const float* __restrict__ bow_b,
    float* __restrict__ lseb, float* __restrict__ out)
{
  __shared__ float red[8];
  const int b = threadIdx.x;
  float se = 0.f;
  for (int i = 0; i < 96; ++i) se += c1p[(size_t)i * B_ + b];
  lseb[b] = __logf(se);
  float het = 0.f, tpc = 0.f;
  #pragma unroll
  for (int k = 0; k < K_; ++k) {
    float th = thetaf[(size_t)b * KP + k];
    het += th * hetmat[(size_t)b * KP + k];
    tpc += th * topic_w[k];
  }
  float ep = het + hetmat[(size_t)b * KP + 50] + bow_b[0] + tpc + topic_b[0];
  float d = ep - labels[b];
  float mse  = blockred512(d * d, red);
  float kl   = blockred512(kldp[b], red);
  float sg = 0.f, sr = 0.f, sw = 0.f;
  for (int i = b; i < NSB; i += 512) { sg += pg[i]; sr += pbr[i]; sw += pbw2[i]; }
  sg = blockred512(sg, red);
  sr = blockred512(sr, red);
  sw = blockred512(sw, red);
  if (b == 0) {
    out[1] = 0.0005f * sr + mse / (float)B_ + 5e-6f * sg + 0.0005f * sqrtf(sw);
    out[2] = -0.5f * kl / (float)B_;
  }
}

// ---------------------------------------------------------------------------
// k_c2: c2p[blk] = partial of sum_bv log(exp(logit-lse)+1e-6)*bows
// ---------------------------------------------------------------------------
__global__ __launch_bounds__(256, 2) void k_c2(
    const short* __restrict__ thetab, const short* __restrict__ betab,
    const float* __restrict__ br, const float* __restrict__ lseb,
    const float* __restrict__ bows, float* __restrict__ c2p)
{
  __shared__ float red[4];
  const int blk = blockIdx.x;
  const int bm = blk & 7, vs = blk >> 3;
  const int lane = threadIdx.x & 63, wv = threadIdx.x >> 6;
  const int l15 = lane & 15, quad = lane >> 4;
  const int b0 = bm * 64 + wv * 16;
  const short8* arow = (const short8*)(thetab + (size_t)(b0 + l15) * KP);
  const short8 a0 = arow[quad], a1 = arow[4 + quad];
  float lse4[4]; const float* bro[4];
  #pragma unroll
  for (int rr = 0; rr < 4; ++rr) {
    lse4[rr] = lseb[b0 + quad * 4 + rr];
    bro[rr] = bows + (size_t)(b0 + quad * 4 + rr) * V_;
  }
  int t0 = vs * 33, t1 = t0 + 33; if (t1 > 3125) t1 = 3125;
  float p = 0.f;
  auto body = [&](int tt) {
    const int v0 = tt * 16;
    const int v = v0 + l15;
    const short8* brow = (const short8*)(betab + (size_t)v * KP);
    short8 q0 = brow[quad], q1 = brow[4 + quad];
    f32x4 acc = {0.f, 0.f, 0.f, 0.f};
    acc = __builtin_amdgcn_mfma_f32_16x16x32_bf16(a0, q0, acc, 0, 0, 0);
    acc = __builtin_amdgcn_mfma_f32_16x16x32_bf16(a1, q1, acc, 0, 0, 0);
    const float brv = br[v];
    #pragma unroll
    for (int rr = 0; rr < 4; ++rr) {
      float l = acc[rr] + brv - lse4[rr];
      float pr = __logf(__expf(l) + 1e-6f);
      p += pr * bro[rr][v];
    }
  };
  int tt = t0;
  for (; tt + 2 <= t1; tt += 2) { body(tt); body(tt + 1); }
  if (tt < t1) body(tt);
  #pragma unroll
  for (int off = 1; off < 64; off <<= 1) p += __shfl_xor(p, off, 64);
  if (lane == 0) red[wv] = p;
  __syncthreads();
  if (threadIdx.x == 0) c2p[blk] = red[0] + red[1] + red[2] + red[3];
}

// k_d2: out[0] = -sum(c2p)/B
__global__ __launch_bounds__(256) void k_d2(
    const float* __restrict__ c2p, float* __restrict__ out)
{
  __shared__ float red[4];
  float s = 0.f;
  for (int i = threadIdx.x; i < 768; i += 256) s += c2p[i];
  #pragma unroll
  for (int off = 1; off < 64; off <<= 1) s += __shfl_xor(s, off, 64);
  if ((threadIdx.x & 63) == 0) red[threadIdx.x >> 6] = s;
  __syncthreads();
  if (threadIdx.x == 0)
    out[0] = -(red[0] + red[1] + red[2] + red[3]) / (float)B_;
}

// ---------------------------------------------------------------------------
extern "C" void kernel_launch(void* const* d_in, const int* in_sizes, int n_in,
                              void* d_out, int out_size, void* d_ws, size_t ws_size,
                              hipStream_t stream)
{
  const float* bows    = (const float*)d_in[0];
  const float* nb      = (const float*)d_in[1];
  const float* labels  = (const float*)d_in[2];
  const float* W1      = (const float*)d_in[3];
  const float* b1      = (const float*)d_in[4];
  const float* W2      = (const float*)d_in[5];
  const float* b2      = (const float*)d_in[6];
  const float* bn1_g   = (const float*)d_in[7];
  const float* bn1_b   = (const float*)d_in[8];
  const float* bn1_m   = (const float*)d_in[9];
  const float* bn1_v   = (const float*)d_in[10];
  const float* bn2_g   = (const float*)d_in[11];
  const float* bn2_b   = (const float*)d_in[12];
  const float* bn2_m   = (const float*)d_in[13];
  const float* bn2_v   = (const float*)d_in[14];
  const float* muW     = (const float*)d_in[15];
  const float* mub     = (const float*)d_in[16];
  const float* lsW     = (const float*)d_in[17];
  const float* lsb     = (const float*)d_in[18];
  const float* beta    = (const float*)d_in[19];
  const float* gamma   = (const float*)d_in[20];
  const float* brates  = (const float*)d_in[21];
  const float* bow_w   = (const float*)d_in[22];
  const float* bow_b   = (const float*)d_in[23];
  const float* topic_w = (const float*)d_in[24];
  const float* topic_b = (const float*)d_in[25];
  float* out = (float*)d_out;

  char* ws = (char*)d_ws;
  size_t off = 0;
  auto take = [&](size_t bytes) { void* p = ws + off; off = (off + bytes + 255) & ~(size_t)255; return p; };

  short* Wcatb   = (short*)take((size_t)NSTEP * 12288 * 2);  // 38.4 MB
  short* nbb     = (short*)take((size_t)NSTEP * 16384 * 2);  // 51.2 MB
  short* betab   = (short*)take((size_t)V_ * 64 * 2);        // 6.4 MB
  short* thetab  = (short*)take((size_t)B_ * KP * 2);
  float* thetaf  = (float*)take((size_t)B_ * KP * 4);
  float* hetmat  = (float*)take((size_t)B_ * KP * 4);
  float* kldp    = (float*)take((size_t)B_ * 4);
  float* c1p     = (float*)take((size_t)96 * B_ * 4);
  float* c2p     = (float*)take((size_t)768 * 4);
  float* lse_    = (float*)take((size_t)B_ * 4);
  float* pg      = (float*)take((size_t)NSB * 4);
  float* pbr     = (float*)take((size_t)NSB * 4);
  float* pbw2    = (float*)take((size_t)NSB * 4);
  float* part1   = (float*)(ws + off);
  size_t remain = (ws_size > off) ? (ws_size - off) : 0;
  int S = (int)(remain / ((size_t)B_ * NW * 4));
  if (S > 64) S = 64;
  if (S < 1)  S = 1;
  const int sps = (NSTEP + S - 1) / S;

  k_prep<<<NCVT + NSB + NACV, 256, 0, stream>>>(
      W1, beta, gamma, brates, bow_w, nb, Wcatb, betab, nbb, pg, pbr, pbw2);
  k_bg  <<<12 * S, 256, 0, stream>>>(nbb, Wcatb, part1, sps);
  k_mlp <<<B_, 320, 0, stream>>>(part1, S, b1, bn1_g, bn1_b, bn1_m, bn1_v,
                                 W2, b2, bn2_g, bn2_b, bn2_m, bn2_v,
                                 muW, mub, lsW, lsb, thetab, thetaf, hetmat, kldp);
  k_c1  <<<8 * 96, 256, 0, stream>>>(thetab, betab, brates, c1p);
  k_d1  <<<1, 512, 0, stream>>>(c1p, kldp, pg, pbr, pbw2, hetmat, thetaf,
                                labels, topic_w, topic_b, bow_b, lse_, out);
  k_c2  <<<8 * 96, 256, 0, stream>>>(thetab, betab, brates, lse_, bows, c2p);
  k_d2  <<<1, 256, 0, stream>>>(c2p, out);
}